// Round 7
// baseline (400.015 us; speedup 1.0000x reference)
//
#include <hip/hip_runtime.h>
#include <hip/hip_bf16.h>

#define NNODES 100000
#define NEDGES 1600000
#define DF 128
#define NC 40
#define NCP 48          // padded fc cols (3 x 16)
#define NB 196          // CSR bins: dst>>9, 512 nodes/bin
#define CH 4096         // edges per binscatter/bincount block
#define MLP_BLOCKS 512  // fused MLP: 2 blocks/CU, 2 waves/SIMD
#define MLP_WAVES (MLP_BLOCKS * 4)
#define ZROW NNODES     // zero feature row appended to B0/B1
#define CVT_BLOCKS 6250 // NNODES*DF/(256*8)

typedef __bf16 bf16x8 __attribute__((ext_vector_type(8)));
typedef float f32x4 __attribute__((ext_vector_type(4)));
typedef float f32x2 __attribute__((ext_vector_type(2)));

__device__ __forceinline__ unsigned short f2bf(float f) {
    unsigned int u = __builtin_bit_cast(unsigned int, f);
    u = (u + 0x7FFFu + ((u >> 16) & 1u)) >> 16;   // RNE
    return (unsigned short)u;
}
__device__ __forceinline__ float bf2f(unsigned short s) {
    unsigned int u = ((unsigned int)s) << 16;
    return __builtin_bit_cast(float, u);
}
__device__ __forceinline__ float bfLo(unsigned int u) {
    return __builtin_bit_cast(float, u << 16);
}
__device__ __forceinline__ float bfHi(unsigned int u) {
    return __builtin_bit_cast(float, u & 0xFFFF0000u);
}
__device__ __forceinline__ f32x2 up2(unsigned int u) {
    return (f32x2){bfLo(u), bfHi(u)};
}

// ---------------- dtype detection (flags[0]: ei is int64; flags[1]: floats are bf16)
// also zeroes binCnt (fused memset).
__global__ void k_detect(const unsigned int* __restrict__ ei32,
                         const unsigned int* __restrict__ x32,
                         int* __restrict__ flags,
                         int* __restrict__ binCnt) {
    __shared__ unsigned int rOr[256];
    __shared__ int rCnt[256];
    for (int i = threadIdx.x; i < NB; i += 256) binCnt[i] = 0;
    unsigned int o = 0; int c = 0;
    for (int i = threadIdx.x; i < 1024; i += 256) o |= ei32[2 * i + 1];
    for (int i = threadIdx.x; i < 4096; i += 256) {
        unsigned int e = (x32[i] >> 7) & 0xFFu;
        c += (e >= 100u && e <= 140u) ? 1 : 0;
    }
    rOr[threadIdx.x] = o; rCnt[threadIdx.x] = c;
    __syncthreads();
    for (int s = 128; s; s >>= 1) {
        if ((int)threadIdx.x < s) {
            rOr[threadIdx.x] |= rOr[threadIdx.x + s];
            rCnt[threadIdx.x] += rCnt[threadIdx.x + s];
        }
        __syncthreads();
    }
    if (threadIdx.x == 0) {
        flags[0] = (rOr[0] == 0u) ? 1 : 0;
        flags[1] = (rCnt[0] > 2457) ? 1 : 0;
    }
}

__device__ __forceinline__ int ldIdx(const void* ei, int flag64, int i) {
    return flag64 ? (int)((const long long*)ei)[i] : ((const int*)ei)[i];
}

// ---------------- fused prep: feature cvt (blocks < CVT_BLOCKS) + weight/bias
// transposes + zero-row pads (remaining blocks). One dispatch.
__global__ __launch_bounds__(256) void k_prep(const void* __restrict__ src,
                                              const void* w1a, const void* w1b,
                                              const void* w2a, const void* w2b,
                                              const void* wfc,
                                              const void* b1a, const void* b1b,
                                              const void* b2a, const void* b2b,
                                              const void* bfc,
                                              const int* __restrict__ flags,
                                              unsigned short* __restrict__ dst,
                                              unsigned short* __restrict__ wAll,
                                              float* __restrict__ bAll,
                                              unsigned short* __restrict__ pad0,
                                              unsigned short* __restrict__ pad1) {
    int bf = flags[1];
    if (blockIdx.x < CVT_BLOCKS) {
        int i = blockIdx.x * 256 + threadIdx.x;   // 8 bf16 elems each
        if (bf) {
            ((uint4*)dst)[i] = ((const uint4*)src)[i];
        } else {
            uint4 a = ((const uint4*)src)[2 * i];
            uint4 b = ((const uint4*)src)[2 * i + 1];
            auto pk = [](unsigned int lo, unsigned int hi) -> unsigned int {
                return ((unsigned int)f2bf(__builtin_bit_cast(float, hi)) << 16) |
                       f2bf(__builtin_bit_cast(float, lo));
            };
            uint4 r;
            r.x = pk(a.x, a.y);
            r.y = pk(a.z, a.w);
            r.z = pk(b.x, b.y);
            r.w = pk(b.z, b.w);
            ((uint4*)dst)[i] = r;
        }
        return;
    }
    int idx = (blockIdx.x - CVT_BLOCKS) * 256 + threadIdx.x;
    auto ldf = [&](const void* p, int i) -> float {
        return bf ? bf2f(((const unsigned short*)p)[i]) : ((const float*)p)[i];
    };
    if (idx < 65536) {                       // 4 square transposes
        int wi = idx >> 14, r = idx & 16383;
        int n = r >> 7, k = r & 127;
        const void* s = (wi == 0) ? w1a : (wi == 1) ? w1b : (wi == 2) ? w2a : w2b;
        wAll[idx] = f2bf(ldf(s, k * 128 + n));
    } else if (idx < 65536 + NCP * 128) {    // wfc transpose, zero pad
        int r = idx - 65536;
        int n = r >> 7, k = r & 127;
        wAll[idx] = (n < NC) ? f2bf(ldf(wfc, k * NC + n)) : (unsigned short)0;
    } else if (idx < 65536 + NCP * 128 + 512 + NC) {
        int r = idx - (65536 + NCP * 128);
        const void* s; int i;
        if (r < 128)      { s = b1a; i = r; }
        else if (r < 256) { s = b1b; i = r - 128; }
        else if (r < 384) { s = b2a; i = r - 256; }
        else if (r < 512) { s = b2b; i = r - 384; }
        else              { s = bfc; i = r - 512; }
        bAll[r] = ldf(s, i);
    } else if (idx < 65536 + NCP * 128 + 512 + NC + 256) {
        pad0[idx - (65536 + NCP * 128 + 512 + NC)] = 0;   // B0 zero row
    } else if (idx < 65536 + NCP * 128 + 512 + NC + 512) {
        pad1[idx - (65536 + NCP * 128 + 512 + NC + 256)] = 0;  // B1 zero row
    }
}

// ================= binned CSR build =================
__global__ __launch_bounds__(256) void k_bincount(const void* __restrict__ ei,
                                                  const int* __restrict__ flags,
                                                  int* __restrict__ binCnt) {
    __shared__ int l[NB];
    int t = threadIdx.x;
    int f64 = flags[0];
    for (int i = t; i < NB; i += 256) l[i] = 0;
    __syncthreads();
    int base = blockIdx.x * CH;
#pragma unroll
    for (int k = 0; k < CH / 256; k++) {
        int e = base + k * 256 + t;
        if (e < NEDGES) atomicAdd(&l[ldIdx(ei, f64, NEDGES + e) >> 9], 1);
    }
    __syncthreads();
    for (int i = t; i < NB; i += 256)
        if (l[i]) atomicAdd(&binCnt[i], l[i]);
}

__global__ __launch_bounds__(256) void k_binscan(const int* __restrict__ binCnt,
                                                 int* __restrict__ binOfs,
                                                 int* __restrict__ binCur) {
    __shared__ int sh[256];
    int t = threadIdx.x;
    int v = (t < NB) ? binCnt[t] : 0;
    sh[t] = v;
    __syncthreads();
    for (int off = 1; off < 256; off <<= 1) {
        int x = (t >= off) ? sh[t - off] : 0;
        __syncthreads();
        sh[t] += x;
        __syncthreads();
    }
    if (t < NB) {
        binOfs[t + 1] = sh[t];
        binCur[t] = sh[t] - v;      // exclusive
    }
    if (t == 0) binOfs[0] = 0;
}

__global__ __launch_bounds__(256) void k_binscatter(const void* __restrict__ ei,
                                                    const int* __restrict__ flags,
                                                    int* __restrict__ binCur,
                                                    int2* __restrict__ ebin) {
    __shared__ int lcnt[NB], lbase[NB], lofs[NB];
    int t = threadIdx.x;
    int f64 = flags[0];
    for (int i = t; i < NB; i += 256) lcnt[i] = 0;
    __syncthreads();
    int base = blockIdx.x * CH;
    int2 ed[CH / 256];
    int bn[CH / 256];
#pragma unroll
    for (int k = 0; k < CH / 256; k++) {
        int e = base + k * 256 + t;
        if (e < NEDGES) {
            ed[k].x = ldIdx(ei, f64, e);
            ed[k].y = ldIdx(ei, f64, NEDGES + e);
            bn[k] = ed[k].y >> 9;
            atomicAdd(&lcnt[bn[k]], 1);
        } else bn[k] = -1;
    }
    __syncthreads();
    if (t < NB) {
        int c = lcnt[t];
        lbase[t] = c ? atomicAdd(&binCur[t], c) : 0;
        lofs[t] = 0;
    }
    __syncthreads();
#pragma unroll
    for (int k = 0; k < CH / 256; k++) {
        if (bn[k] >= 0) {
            int p = lbase[bn[k]] + atomicAdd(&lofs[bn[k]], 1);
            ebin[p] = ed[k];
        }
    }
}

__global__ __launch_bounds__(256) void k_binfill(const int2* __restrict__ ebin,
                                                 const int* __restrict__ binOfs,
                                                 int* __restrict__ rowptr,
                                                 int* __restrict__ perm) {
    __shared__ int deg[512], lptr[512], ssum[256];
    int b = blockIdx.x, t = threadIdx.x;
    int n0 = b << 9;
    int nn = NNODES - n0; if (nn > 512) nn = 512;
    int e0 = binOfs[b], e1 = binOfs[b + 1];
    deg[t] = 0; deg[t + 256] = 0;
    __syncthreads();
    for (int e = e0 + t; e < e1; e += 256)
        atomicAdd(&deg[ebin[e].y - n0], 1);
    __syncthreads();
    int d0 = deg[2 * t], d1 = deg[2 * t + 1];
    int s = d0 + d1;
    ssum[t] = s;
    __syncthreads();
    for (int off = 1; off < 256; off <<= 1) {
        int x = (t >= off) ? ssum[t - off] : 0;
        __syncthreads();
        ssum[t] += x;
        __syncthreads();
    }
    int ex = ssum[t] - s;
    lptr[2 * t] = ex;
    lptr[2 * t + 1] = ex + d0;
    if (2 * t < nn)     rowptr[n0 + 2 * t] = e0 + ex;
    if (2 * t + 1 < nn) rowptr[n0 + 2 * t + 1] = e0 + ex + d0;
    if (b == NB - 1 && t == 0) rowptr[NNODES] = e1;
    deg[2 * t] = 0; deg[2 * t + 1] = 0;   // reuse as cursor
    __syncthreads();
    for (int e = e0 + t; e < e1; e += 256) {
        int2 ed = ebin[e];
        int d = ed.y - n0;
        int pos = e0 + lptr[d] + atomicAdd(&deg[d], 1);
        perm[pos] = ed.x;
    }
}

// ================= gather aggregation (R4 best: 57.0us, at pattern ceiling) ==
__device__ __forceinline__ void accu(f32x2* acc, uint4 u) {
    acc[0] += up2(u.x);
    acc[1] += up2(u.y);
    acc[2] += up2(u.z);
    acc[3] += up2(u.w);
}

template <int S>
__device__ __forceinline__ void gslots(const int* __restrict__ perm, const uint4* __restrict__ F,
                                       int j, int je, int g, int c, f32x2* acc) {
    int pm[S];
#pragma unroll
    for (int k = 0; k < S; k++) pm[k] = perm[j + 4 * k + g];
#pragma unroll
    for (int k = 0; k < S; k++)
        if (j + 4 * k + g >= je) pm[k] = ZROW;       // value-clamp, off the addr-issue path
    uint4 u[S];
#pragma unroll
    for (int k = 0; k < S; k++) u[k] = F[pm[k] * 16 + c];
#pragma unroll
    for (int k = 0; k < S; k++) accu(acc, u[k]);
}

__global__ __launch_bounds__(256) void k_gather(const unsigned short* __restrict__ feat,
                                                const unsigned short* __restrict__ x,
                                                const int* __restrict__ rowptr,
                                                const int* __restrict__ perm,
                                                unsigned short* __restrict__ out) {
    int wave = threadIdx.x >> 6, lane = threadIdx.x & 63;
    int i = blockIdx.x * 4 + wave;        // NNODES = 25000*4 exactly
    int g = lane >> 4, c = lane & 15;
    const uint4* F = (const uint4*)feat;  // one row = 16 uint4

    uint4 xv = ((const uint4*)x)[i * 16 + c];
    int jb = rowptr[i], je = rowptr[i + 1];

    f32x2 acc[4];
#pragma unroll
    for (int k = 0; k < 4; k++) acc[k] = (f32x2){0.f, 0.f};

    int j = jb;
    while (je - j > 24) {
        int s0 = perm[j + g], s1 = perm[j + 4 + g];
        int s2 = perm[j + 8 + g], s3 = perm[j + 12 + g];
        uint4 u0 = F[s0 * 16 + c];
        uint4 u1 = F[s1 * 16 + c];
        uint4 u2 = F[s2 * 16 + c];
        uint4 u3 = F[s3 * 16 + c];
        accu(acc, u0); accu(acc, u1); accu(acc, u2); accu(acc, u3);
        j += 16;
    }
    int deg = je - j;                     // 0..24, wave-uniform
    if (deg > 16)      gslots<6>(perm, F, j, je, g, c, acc);
    else if (deg > 8)  gslots<4>(perm, F, j, je, g, c, acc);
    else if (deg > 0)  gslots<2>(perm, F, j, je, g, c, acc);

#pragma unroll
    for (int k = 0; k < 4; k++) {
        acc[k][0] += __shfl_xor(acc[k][0], 16);
        acc[k][1] += __shfl_xor(acc[k][1], 16);
        acc[k][0] += __shfl_xor(acc[k][0], 32);
        acc[k][1] += __shfl_xor(acc[k][1], 32);
    }

    acc[0] += up2(xv.x);
    acc[1] += up2(xv.y);
    acc[2] += up2(xv.z);
    acc[3] += up2(xv.w);

    if (g == 0) {
        uint4 r;
        r.x = ((unsigned int)f2bf(acc[0][1]) << 16) | f2bf(acc[0][0]);
        r.y = ((unsigned int)f2bf(acc[1][1]) << 16) | f2bf(acc[1][0]);
        r.z = ((unsigned int)f2bf(acc[2][1]) << 16) | f2bf(acc[2][0]);
        r.w = ((unsigned int)f2bf(acc[3][1]) << 16) | f2bf(acc[3][0]);
        ((uint4*)out)[i * 16 + c] = r;
    }
}

// ================= fused GIN MLP v2: out = relu(relu(A@Wa+ba)@Wb+bb) ==========
// Occupancy-first rework of R6 (1 wave/SIMD was the bottleneck): Wa register-
// resident (128 VGPR); Wb (+Wfc if DOFC) in block-shared LDS, chunk-XOR
// swizzled (idx = row*128 + ((col>>3 ^ (row&15))<<3) + (col&7)) so all
// ds_read_b128 are alias-free with zero padding. VGPR ~240 -> 2 waves/SIMD,
// LDS 48/60KB -> 2 blocks/CU. B-frags re-read from LDS per tile (~625MB
// aggregate @69TB/s ~ 9us floor). Redistribute tile per wave: 16x128 u16,
// same swizzle. Layouts (m89/m91): A[m][k=quad*8+j]; B[k][n]; D col=lane&15,
// row=quad*4+reg.
template <bool DOFC>
__global__ __launch_bounds__(256, 2) void k_mlp_rb(const unsigned short* __restrict__ A,
                                                   const unsigned short* __restrict__ WaT,
                                                   const float* __restrict__ ba,
                                                   const unsigned short* __restrict__ WbT,
                                                   const float* __restrict__ bb,
                                                   const unsigned short* __restrict__ WfcT,
                                                   const float* __restrict__ bfc,
                                                   const int* __restrict__ flags,
                                                   unsigned short* __restrict__ outH,
                                                   void* __restrict__ outFC) {
    __shared__ __align__(16) unsigned short sWb[16384];              // 128x128 swizzled
    __shared__ __align__(16) unsigned short sWf[DOFC ? 6144 : 16];   // 48x128 swizzled
    __shared__ __align__(16) unsigned short sT[4][2048];             // per-wave 16x128

    int wave = threadIdx.x >> 6, lane = threadIdx.x & 63;
    int gw = blockIdx.x * 4 + wave;
    int m = lane & 15, quad = lane >> 4;
    unsigned short* T = sT[wave];

    // stage Wb (and Wfc) into swizzled LDS
    for (int idx = threadIdx.x; idx < 16384; idx += 256) {
        int n = idx >> 7, k = idx & 127;
        sWb[(n << 7) | (((k >> 3) ^ (n & 15)) << 3) | (k & 7)] = WbT[idx];
    }
    if (DOFC) {
        for (int idx = threadIdx.x; idx < 6144; idx += 256) {
            int n = idx >> 7, k = idx & 127;
            sWf[(n << 7) | (((k >> 3) ^ (n & 15)) << 3) | (k & 7)] = WfcT[idx];
        }
    }

    // Wa register-resident
    bf16x8 wa[8][4];
#pragma unroll
    for (int nt = 0; nt < 8; nt++) {
        const unsigned short* Ba = WaT + (nt * 16 + m) * DF + quad * 8;
#pragma unroll
        for (int ks = 0; ks < 4; ks++)
            wa[nt][ks] = *(const bf16x8*)(Ba + ks * 32);
    }
    float bva[8], bvb[8];
#pragma unroll
    for (int nt = 0; nt < 8; nt++) { bva[nt] = ba[nt * 16 + m]; bvb[nt] = bb[nt * 16 + m]; }
    float fv0 = 0.f, fv1 = 0.f, fv2 = 0.f;
    bool valid2 = (m < 8);
    int obf = 0;
    if (DOFC) {
        fv0 = bfc[m]; fv1 = bfc[16 + m];
        fv2 = valid2 ? bfc[32 + m] : 0.f;
        obf = flags[1];
    }
    __syncthreads();

    // swizzled u16 index within a 16/48/128-row x 128-col tile
    auto ladr = [](int row, int col) -> int {
        return (row << 7) | (((col >> 3) ^ (row & 15)) << 3) | (col & 7);
    };

    for (int tile = gw; tile < NNODES / 16; tile += MLP_WAVES) {
        int r0 = tile * 16;
        const unsigned short* Ab = A + (r0 + m) * DF + quad * 8;
        bf16x8 a[4];
#pragma unroll
        for (int ks = 0; ks < 4; ks++) a[ks] = *(const bf16x8*)(Ab + ks * 32);

        f32x4 acc[8];
#pragma unroll
        for (int nt = 0; nt < 8; nt++) acc[nt] = (f32x4){0.f, 0.f, 0.f, 0.f};
#pragma unroll
        for (int nt = 0; nt < 8; nt++)
#pragma unroll
            for (int ks = 0; ks < 4; ks++)
                acc[nt] = __builtin_amdgcn_mfma_f32_16x16x32_bf16(a[ks], wa[nt][ks], acc[nt], 0, 0, 0);

        // stage-1 epilogue -> wave-private LDS tile (relu'd bf16)
#pragma unroll
        for (int nt = 0; nt < 8; nt++)
#pragma unroll
            for (int reg = 0; reg < 4; reg++) {
                float v = acc[nt][reg] + bva[nt];
                if (v < 0.f) v = 0.f;
                T[ladr(quad * 4 + reg, nt * 16 + m)] = f2bf(v);
            }

        // stage-2: A-frags from tile (row m), B-frags from sWb
        bf16x8 a2[4];
#pragma unroll
        for (int ks = 0; ks < 4; ks++)
            a2[ks] = *(const bf16x8*)&T[(m << 7) | ((((ks << 2) + quad) ^ m) << 3)];
#pragma unroll
        for (int nt = 0; nt < 8; nt++) acc[nt] = (f32x4){0.f, 0.f, 0.f, 0.f};
#pragma unroll
        for (int nt = 0; nt < 8; nt++) {
            bf16x8 wbf[4];
#pragma unroll
            for (int ks = 0; ks < 4; ks++)
                wbf[ks] = *(const bf16x8*)&sWb[((nt * 16 + m) << 7) | ((((ks << 2) + quad) ^ m) << 3)];
#pragma unroll
            for (int ks = 0; ks < 4; ks++)
                acc[nt] = __builtin_amdgcn_mfma_f32_16x16x32_bf16(a2[ks], wbf[ks], acc[nt], 0, 0, 0);
        }

        if (!DOFC) {
#pragma unroll
            for (int nt = 0; nt < 8; nt++) {
                int col = nt * 16 + m;
#pragma unroll
                for (int reg = 0; reg < 4; reg++) {
                    int row = r0 + quad * 4 + reg;
                    float v = acc[nt][reg] + bvb[nt];
                    if (v < 0.f) v = 0.f;
                    outH[row * DF + col] = f2bf(v);
                }
            }
        } else {
            // h2 -> tile (same-wave DS ops are in-order after the reads above)
#pragma unroll
            for (int nt = 0; nt < 8; nt++)
#pragma unroll
                for (int reg = 0; reg < 4; reg++) {
                    float v = acc[nt][reg] + bvb[nt];
                    if (v < 0.f) v = 0.f;
                    T[ladr(quad * 4 + reg, nt * 16 + m)] = f2bf(v);
                }
            bf16x8 a3[4];
#pragma unroll
            for (int ks = 0; ks < 4; ks++)
                a3[ks] = *(const bf16x8*)&T[(m << 7) | ((((ks << 2) + quad) ^ m) << 3)];
            f32x4 fa[3];
#pragma unroll
            for (int nt = 0; nt < 3; nt++) fa[nt] = (f32x4){0.f, 0.f, 0.f, 0.f};
#pragma unroll
            for (int nt = 0; nt < 3; nt++) {
                bf16x8 wff[4];
#pragma unroll
                for (int ks = 0; ks < 4; ks++)
                    wff[ks] = *(const bf16x8*)&sWf[((nt * 16 + m) << 7) | ((((ks << 2) + quad) ^ m) << 3)];
#pragma unroll
                for (int ks = 0; ks < 4; ks++)
                    fa[nt] = __builtin_amdgcn_mfma_f32_16x16x32_bf16(a3[ks], wff[ks], fa[nt], 0, 0, 0);
            }

#pragma unroll
            for (int reg = 0; reg < 4; reg++) {
                float v0 = fa[0][reg] + fv0;
                float v1 = fa[1][reg] + fv1;
                float v2 = valid2 ? (fa[2][reg] + fv2) : -3.0e38f;
                float mx = fmaxf(fmaxf(v0, v1), v2);
#pragma unroll
                for (int off = 1; off < 16; off <<= 1) mx = fmaxf(mx, __shfl_xor(mx, off, 16));
                float e = __expf(v0 - mx) + __expf(v1 - mx) + (valid2 ? __expf(v2 - mx) : 0.f);
#pragma unroll
                for (int off = 1; off < 16; off <<= 1) e += __shfl_xor(e, off, 16);
                float l = mx + __logf(e);
                int row = r0 + quad * 4 + reg;
                if (obf) {
                    unsigned short* o = (unsigned short*)outFC + row * NC;
                    o[m] = f2bf(v0 - l);
                    o[16 + m] = f2bf(v1 - l);
                    if (valid2) o[32 + m] = f2bf(v2 - l);
                } else {
                    float* o = (float*)outFC + row * NC;
                    o[m] = v0 - l;
                    o[16 + m] = v1 - l;
                    if (valid2) o[32 + m] = v2 - l;
                }
            }
        }
    }
}

extern "C" void kernel_launch(void* const* d_in, const int* in_sizes, int n_in,
                              void* d_out, int out_size, void* d_ws, size_t ws_size,
                              hipStream_t stream) {
    const void* x   = d_in[0];
    const void* ei  = d_in[1];
    const void* w1a = d_in[2];
    const void* b1a = d_in[3];
    const void* w1b = d_in[4];
    const void* b1b = d_in[5];
    const void* w2a = d_in[6];
    const void* b2a = d_in[7];
    const void* w2b = d_in[8];
    const void* b2b = d_in[9];
    const void* wfc = d_in[10];
    const void* bfc = d_in[11];

    char* ws = (char*)d_ws;
    size_t off = 0;
    auto alloc = [&](size_t bytes) {
        void* p = ws + off;
        off += (bytes + 255) & ~(size_t)255;
        return p;
    };
    // B0/B1 have one extra zeroed row (ZROW) for the gather's slot clamp.
    unsigned short* B0    = (unsigned short*)alloc((size_t)(NNODES + 1) * DF * 2);
    unsigned short* B1    = (unsigned short*)alloc((size_t)(NNODES + 1) * DF * 2);
    int2*           ebin  = (int2*)alloc((size_t)NEDGES * 8);
    int*            perm  = (int*)alloc((size_t)(NEDGES + 64) * 4);   // +64 pad: slot over-read
    int*            rowptr= (int*)alloc((size_t)(NNODES + 1) * 4);
    int*            binCnt= (int*)alloc(NB * 4);
    int*            binOfs= (int*)alloc((NB + 1) * 4);
    int*            binCur= (int*)alloc(NB * 4);
    int*            flags = (int*)alloc(256);
    unsigned short* wAll  = (unsigned short*)alloc((4 * 16384 + NCP * 128) * 2);
    float*          bAll  = (float*)alloc((512 + NC) * 4);

    unsigned short* w1aT = wAll;
    unsigned short* w1bT = wAll + 16384;
    unsigned short* w2aT = wAll + 32768;
    unsigned short* w2bT = wAll + 49152;
    unsigned short* wfcT = wAll + 65536;
    float* b1af = bAll;
    float* b1bf = bAll + 128;
    float* b2af = bAll + 256;
    float* b2bf = bAll + 384;
    float* bfcf = bAll + 512;

    // ---- dtype detection (+ binCnt zero), then fused cvt + weight prep
    k_detect<<<1, 256, 0, stream>>>((const unsigned int*)ei, (const unsigned int*)x, flags, binCnt);
    int wprepN = 4 * 16384 + NCP * 128 + 512 + NC + 512;
    int prepGrid = CVT_BLOCKS + (wprepN + 255) / 256;
    k_prep<<<prepGrid, 256, 0, stream>>>(x, w1a, w1b, w2a, w2b, wfc,
                                         b1a, b1b, b2a, b2b, bfc,
                                         flags, B0, wAll, bAll,
                                         B0 + (size_t)NNODES * DF,
                                         B1 + (size_t)NNODES * DF);

    // ---- binned CSR build (reads edge_index directly)
    int nEB = (NEDGES + CH - 1) / CH;                          // 391
    k_bincount<<<nEB, 256, 0, stream>>>(ei, flags, binCnt);
    k_binscan<<<1, 256, 0, stream>>>(binCnt, binOfs, binCur);
    k_binscatter<<<nEB, 256, 0, stream>>>(ei, flags, binCur, ebin);
    k_binfill<<<NB, 256, 0, stream>>>(ebin, binOfs, rowptr, perm);

    const int gatherGrid = NNODES / 4;                         // 25000

    // ---- layer 1: gather -> fused MLP (h1 into B0; its ZROW pad stays zero)
    k_gather<<<gatherGrid, 256, 0, stream>>>(B0, B0, rowptr, perm, B1);
    k_mlp_rb<false><<<MLP_BLOCKS, 256, 0, stream>>>(B1, w1aT, b1af, w1bT, b1bf,
                                                    nullptr, nullptr, flags, B0, nullptr);

    // ---- layer 2: gather -> fused MLP + fc + log_softmax (h2 never hits global)
    k_gather<<<gatherGrid, 256, 0, stream>>>(B0, B0, rowptr, perm, B1);
    k_mlp_rb<true><<<MLP_BLOCKS, 256, 0, stream>>>(B1, w2aT, b2af, w2bT, b2bf,
                                                   wfcT, bfcf, flags, nullptr, d_out);
}

// Round 8
// 378.347 us; speedup vs baseline: 1.0573x; 1.0573x over previous
//
#include <hip/hip_runtime.h>
#include <hip/hip_bf16.h>

#define NNODES 100000
#define NEDGES 1600000
#define DF 128
#define NC 40
#define NCP 48          // padded fc cols (3 x 16)
#define NB 196          // CSR bins: dst>>9, 512 nodes/bin
#define CH 4096         // edges per binscatter/bincount block
#define MLP_BLOCKS 512  // fused MLP: 2 blocks/CU (80KB LDS each), 2 waves/SIMD
#define MLP_WAVES (MLP_BLOCKS * 4)
#define ZROW NNODES     // zero feature row appended to B0/B1
#define CVT_BLOCKS 6250 // NNODES*DF/(256*8)

typedef __bf16 bf16x8 __attribute__((ext_vector_type(8)));
typedef float f32x4 __attribute__((ext_vector_type(4)));
typedef float f32x2 __attribute__((ext_vector_type(2)));

__device__ __forceinline__ unsigned short f2bf(float f) {
    unsigned int u = __builtin_bit_cast(unsigned int, f);
    u = (u + 0x7FFFu + ((u >> 16) & 1u)) >> 16;   // RNE
    return (unsigned short)u;
}
__device__ __forceinline__ float bf2f(unsigned short s) {
    unsigned int u = ((unsigned int)s) << 16;
    return __builtin_bit_cast(float, u);
}
__device__ __forceinline__ float bfLo(unsigned int u) {
    return __builtin_bit_cast(float, u << 16);
}
__device__ __forceinline__ float bfHi(unsigned int u) {
    return __builtin_bit_cast(float, u & 0xFFFF0000u);
}
__device__ __forceinline__ f32x2 up2(unsigned int u) {
    return (f32x2){bfLo(u), bfHi(u)};
}

// ---------------- dtype detection (flags[0]: ei is int64; flags[1]: floats are bf16)
// also zeroes binCnt (fused memset).
__global__ void k_detect(const unsigned int* __restrict__ ei32,
                         const unsigned int* __restrict__ x32,
                         int* __restrict__ flags,
                         int* __restrict__ binCnt) {
    __shared__ unsigned int rOr[256];
    __shared__ int rCnt[256];
    for (int i = threadIdx.x; i < NB; i += 256) binCnt[i] = 0;
    unsigned int o = 0; int c = 0;
    for (int i = threadIdx.x; i < 1024; i += 256) o |= ei32[2 * i + 1];
    for (int i = threadIdx.x; i < 4096; i += 256) {
        unsigned int e = (x32[i] >> 7) & 0xFFu;
        c += (e >= 100u && e <= 140u) ? 1 : 0;
    }
    rOr[threadIdx.x] = o; rCnt[threadIdx.x] = c;
    __syncthreads();
    for (int s = 128; s; s >>= 1) {
        if ((int)threadIdx.x < s) {
            rOr[threadIdx.x] |= rOr[threadIdx.x + s];
            rCnt[threadIdx.x] += rCnt[threadIdx.x + s];
        }
        __syncthreads();
    }
    if (threadIdx.x == 0) {
        flags[0] = (rOr[0] == 0u) ? 1 : 0;
        flags[1] = (rCnt[0] > 2457) ? 1 : 0;
    }
}

__device__ __forceinline__ int ldIdx(const void* ei, int flag64, int i) {
    return flag64 ? (int)((const long long*)ei)[i] : ((const int*)ei)[i];
}

// ---------------- fused prep: feature cvt (blocks < CVT_BLOCKS) + weight/bias
// transposes + zero-row pads (remaining blocks). One dispatch.
__global__ __launch_bounds__(256) void k_prep(const void* __restrict__ src,
                                              const void* w1a, const void* w1b,
                                              const void* w2a, const void* w2b,
                                              const void* wfc,
                                              const void* b1a, const void* b1b,
                                              const void* b2a, const void* b2b,
                                              const void* bfc,
                                              const int* __restrict__ flags,
                                              unsigned short* __restrict__ dst,
                                              unsigned short* __restrict__ wAll,
                                              float* __restrict__ bAll,
                                              unsigned short* __restrict__ pad0,
                                              unsigned short* __restrict__ pad1) {
    int bf = flags[1];
    if (blockIdx.x < CVT_BLOCKS) {
        int i = blockIdx.x * 256 + threadIdx.x;   // 8 bf16 elems each
        if (bf) {
            ((uint4*)dst)[i] = ((const uint4*)src)[i];
        } else {
            uint4 a = ((const uint4*)src)[2 * i];
            uint4 b = ((const uint4*)src)[2 * i + 1];
            auto pk = [](unsigned int lo, unsigned int hi) -> unsigned int {
                return ((unsigned int)f2bf(__builtin_bit_cast(float, hi)) << 16) |
                       f2bf(__builtin_bit_cast(float, lo));
            };
            uint4 r;
            r.x = pk(a.x, a.y);
            r.y = pk(a.z, a.w);
            r.z = pk(b.x, b.y);
            r.w = pk(b.z, b.w);
            ((uint4*)dst)[i] = r;
        }
        return;
    }
    int idx = (blockIdx.x - CVT_BLOCKS) * 256 + threadIdx.x;
    auto ldf = [&](const void* p, int i) -> float {
        return bf ? bf2f(((const unsigned short*)p)[i]) : ((const float*)p)[i];
    };
    if (idx < 65536) {                       // 4 square transposes
        int wi = idx >> 14, r = idx & 16383;
        int n = r >> 7, k = r & 127;
        const void* s = (wi == 0) ? w1a : (wi == 1) ? w1b : (wi == 2) ? w2a : w2b;
        wAll[idx] = f2bf(ldf(s, k * 128 + n));
    } else if (idx < 65536 + NCP * 128) {    // wfc transpose, zero pad
        int r = idx - 65536;
        int n = r >> 7, k = r & 127;
        wAll[idx] = (n < NC) ? f2bf(ldf(wfc, k * NC + n)) : (unsigned short)0;
    } else if (idx < 65536 + NCP * 128 + 512 + NC) {
        int r = idx - (65536 + NCP * 128);
        const void* s; int i;
        if (r < 128)      { s = b1a; i = r; }
        else if (r < 256) { s = b1b; i = r - 128; }
        else if (r < 384) { s = b2a; i = r - 256; }
        else if (r < 512) { s = b2b; i = r - 384; }
        else              { s = bfc; i = r - 512; }
        bAll[r] = ldf(s, i);
    } else if (idx < 65536 + NCP * 128 + 512 + NC + 256) {
        pad0[idx - (65536 + NCP * 128 + 512 + NC)] = 0;   // B0 zero row
    } else if (idx < 65536 + NCP * 128 + 512 + NC + 512) {
        pad1[idx - (65536 + NCP * 128 + 512 + NC + 256)] = 0;  // B1 zero row
    }
}

// ================= binned CSR build =================
__global__ __launch_bounds__(256) void k_bincount(const void* __restrict__ ei,
                                                  const int* __restrict__ flags,
                                                  int* __restrict__ binCnt) {
    __shared__ int l[NB];
    int t = threadIdx.x;
    int f64 = flags[0];
    for (int i = t; i < NB; i += 256) l[i] = 0;
    __syncthreads();
    int base = blockIdx.x * CH;
#pragma unroll
    for (int k = 0; k < CH / 256; k++) {
        int e = base + k * 256 + t;
        if (e < NEDGES) atomicAdd(&l[ldIdx(ei, f64, NEDGES + e) >> 9], 1);
    }
    __syncthreads();
    for (int i = t; i < NB; i += 256)
        if (l[i]) atomicAdd(&binCnt[i], l[i]);
}

__global__ __launch_bounds__(256) void k_binscan(const int* __restrict__ binCnt,
                                                 int* __restrict__ binOfs,
                                                 int* __restrict__ binCur) {
    __shared__ int sh[256];
    int t = threadIdx.x;
    int v = (t < NB) ? binCnt[t] : 0;
    sh[t] = v;
    __syncthreads();
    for (int off = 1; off < 256; off <<= 1) {
        int x = (t >= off) ? sh[t - off] : 0;
        __syncthreads();
        sh[t] += x;
        __syncthreads();
    }
    if (t < NB) {
        binOfs[t + 1] = sh[t];
        binCur[t] = sh[t] - v;      // exclusive
    }
    if (t == 0) binOfs[0] = 0;
}

__global__ __launch_bounds__(256) void k_binscatter(const void* __restrict__ ei,
                                                    const int* __restrict__ flags,
                                                    int* __restrict__ binCur,
                                                    int2* __restrict__ ebin) {
    __shared__ int lcnt[NB], lbase[NB], lofs[NB];
    int t = threadIdx.x;
    int f64 = flags[0];
    for (int i = t; i < NB; i += 256) lcnt[i] = 0;
    __syncthreads();
    int base = blockIdx.x * CH;
    int2 ed[CH / 256];
    int bn[CH / 256];
#pragma unroll
    for (int k = 0; k < CH / 256; k++) {
        int e = base + k * 256 + t;
        if (e < NEDGES) {
            ed[k].x = ldIdx(ei, f64, e);
            ed[k].y = ldIdx(ei, f64, NEDGES + e);
            bn[k] = ed[k].y >> 9;
            atomicAdd(&lcnt[bn[k]], 1);
        } else bn[k] = -1;
    }
    __syncthreads();
    if (t < NB) {
        int c = lcnt[t];
        lbase[t] = c ? atomicAdd(&binCur[t], c) : 0;
        lofs[t] = 0;
    }
    __syncthreads();
#pragma unroll
    for (int k = 0; k < CH / 256; k++) {
        if (bn[k] >= 0) {
            int p = lbase[bn[k]] + atomicAdd(&lofs[bn[k]], 1);
            ebin[p] = ed[k];
        }
    }
}

__global__ __launch_bounds__(256) void k_binfill(const int2* __restrict__ ebin,
                                                 const int* __restrict__ binOfs,
                                                 int* __restrict__ rowptr,
                                                 int* __restrict__ perm) {
    __shared__ int deg[512], lptr[512], ssum[256];
    int b = blockIdx.x, t = threadIdx.x;
    int n0 = b << 9;
    int nn = NNODES - n0; if (nn > 512) nn = 512;
    int e0 = binOfs[b], e1 = binOfs[b + 1];
    deg[t] = 0; deg[t + 256] = 0;
    __syncthreads();
    for (int e = e0 + t; e < e1; e += 256)
        atomicAdd(&deg[ebin[e].y - n0], 1);
    __syncthreads();
    int d0 = deg[2 * t], d1 = deg[2 * t + 1];
    int s = d0 + d1;
    ssum[t] = s;
    __syncthreads();
    for (int off = 1; off < 256; off <<= 1) {
        int x = (t >= off) ? ssum[t - off] : 0;
        __syncthreads();
        ssum[t] += x;
        __syncthreads();
    }
    int ex = ssum[t] - s;
    lptr[2 * t] = ex;
    lptr[2 * t + 1] = ex + d0;
    if (2 * t < nn)     rowptr[n0 + 2 * t] = e0 + ex;
    if (2 * t + 1 < nn) rowptr[n0 + 2 * t + 1] = e0 + ex + d0;
    if (b == NB - 1 && t == 0) rowptr[NNODES] = e1;
    deg[2 * t] = 0; deg[2 * t + 1] = 0;   // reuse as cursor
    __syncthreads();
    for (int e = e0 + t; e < e1; e += 256) {
        int2 ed = ebin[e];
        int d = ed.y - n0;
        int pos = e0 + lptr[d] + atomicAdd(&deg[d], 1);
        perm[pos] = ed.x;
    }
}

// ================= gather aggregation (R4 best: 57.0us, at pattern ceiling) ==
__device__ __forceinline__ void accu(f32x2* acc, uint4 u) {
    acc[0] += up2(u.x);
    acc[1] += up2(u.y);
    acc[2] += up2(u.z);
    acc[3] += up2(u.w);
}

template <int S>
__device__ __forceinline__ void gslots(const int* __restrict__ perm, const uint4* __restrict__ F,
                                       int j, int je, int g, int c, f32x2* acc) {
    int pm[S];
#pragma unroll
    for (int k = 0; k < S; k++) pm[k] = perm[j + 4 * k + g];
#pragma unroll
    for (int k = 0; k < S; k++)
        if (j + 4 * k + g >= je) pm[k] = ZROW;       // value-clamp, off the addr-issue path
    uint4 u[S];
#pragma unroll
    for (int k = 0; k < S; k++) u[k] = F[pm[k] * 16 + c];
#pragma unroll
    for (int k = 0; k < S; k++) accu(acc, u[k]);
}

__global__ __launch_bounds__(256) void k_gather(const unsigned short* __restrict__ feat,
                                                const unsigned short* __restrict__ x,
                                                const int* __restrict__ rowptr,
                                                const int* __restrict__ perm,
                                                unsigned short* __restrict__ out) {
    int wave = threadIdx.x >> 6, lane = threadIdx.x & 63;
    int i = blockIdx.x * 4 + wave;        // NNODES = 25000*4 exactly
    int g = lane >> 4, c = lane & 15;
    const uint4* F = (const uint4*)feat;  // one row = 16 uint4

    uint4 xv = ((const uint4*)x)[i * 16 + c];
    int jb = rowptr[i], je = rowptr[i + 1];

    f32x2 acc[4];
#pragma unroll
    for (int k = 0; k < 4; k++) acc[k] = (f32x2){0.f, 0.f};

    int j = jb;
    while (je - j > 24) {
        int s0 = perm[j + g], s1 = perm[j + 4 + g];
        int s2 = perm[j + 8 + g], s3 = perm[j + 12 + g];
        uint4 u0 = F[s0 * 16 + c];
        uint4 u1 = F[s1 * 16 + c];
        uint4 u2 = F[s2 * 16 + c];
        uint4 u3 = F[s3 * 16 + c];
        accu(acc, u0); accu(acc, u1); accu(acc, u2); accu(acc, u3);
        j += 16;
    }
    int deg = je - j;                     // 0..24, wave-uniform
    if (deg > 16)      gslots<6>(perm, F, j, je, g, c, acc);
    else if (deg > 8)  gslots<4>(perm, F, j, je, g, c, acc);
    else if (deg > 0)  gslots<2>(perm, F, j, je, g, c, acc);

#pragma unroll
    for (int k = 0; k < 4; k++) {
        acc[k][0] += __shfl_xor(acc[k][0], 16);
        acc[k][1] += __shfl_xor(acc[k][1], 16);
        acc[k][0] += __shfl_xor(acc[k][0], 32);
        acc[k][1] += __shfl_xor(acc[k][1], 32);
    }

    acc[0] += up2(xv.x);
    acc[1] += up2(xv.y);
    acc[2] += up2(xv.z);
    acc[3] += up2(xv.w);

    if (g == 0) {
        uint4 r;
        r.x = ((unsigned int)f2bf(acc[0][1]) << 16) | f2bf(acc[0][0]);
        r.y = ((unsigned int)f2bf(acc[1][1]) << 16) | f2bf(acc[1][0]);
        r.z = ((unsigned int)f2bf(acc[2][1]) << 16) | f2bf(acc[2][0]);
        r.w = ((unsigned int)f2bf(acc[3][1]) << 16) | f2bf(acc[3][0]);
        ((uint4*)out)[i * 16 + c] = r;
    }
}

// ================= fused GIN MLP v3: out = relu(relu(A@Wa+ba)@Wb+bb) ==========
// R7 post-mortem: reg-resident weights + launch_bounds(256,2) -> scratch spill
// (VGPR capped 128, FETCH/WRITE +60MB symmetric, all pipes idle). v3 keeps NO
// large register arrays: Wa AND Wb live in block-shared chunk-XOR-swizzled LDS
// (the swizzle permutes 16B chunks: u128 idx n*16 + ((k>>3) ^ (n&15)), so
// staging is plain uint4 copies and every ds_read_b128 is alias-free).
// LDS = 32+32+16(sT) = exactly 80KB -> 2 blocks/CU; VGPR ~150 (DOFC ~200,
// wfc register-resident 48) -> 2 waves/SIMD, no spill. Per 16-row tile:
// 4 A-loads, 32 Wa-frag LDS reads + 32 MFMA, relu -> per-wave T redistrib,
// 32 Wb-frag reads + 32 MFMA. DOFC adds T roundtrip + 12 MFMA + log_softmax.
// Layouts (m89/m91): A[m][k=quad*8+j]; B[k][n]; D col=lane&15, row=quad*4+reg.
template <bool DOFC>
__global__ __launch_bounds__(256, 2) void k_mlp_lds(const unsigned short* __restrict__ A,
                                                    const unsigned short* __restrict__ WaT,
                                                    const float* __restrict__ ba,
                                                    const unsigned short* __restrict__ WbT,
                                                    const float* __restrict__ bb,
                                                    const unsigned short* __restrict__ WfcT,
                                                    const float* __restrict__ bfc,
                                                    const int* __restrict__ flags,
                                                    unsigned short* __restrict__ outH,
                                                    void* __restrict__ outFC) {
    __shared__ __align__(16) unsigned short sWa[16384];   // 128x128 swizzled
    __shared__ __align__(16) unsigned short sWb[16384];   // 128x128 swizzled
    __shared__ __align__(16) unsigned short sT[4][2048];  // per-wave 16x128 swizzled

    int wave = threadIdx.x >> 6, lane = threadIdx.x & 63;
    int gw = blockIdx.x * 4 + wave;
    int m = lane & 15, quad = lane >> 4;
    unsigned short* T = sT[wave];

    // stage Wa+Wb into swizzled LDS: 16B-chunk permutation -> uint4 copies
    {
        const uint4* Wa4 = (const uint4*)WaT;
        const uint4* Wb4 = (const uint4*)WbT;
        uint4* sA4 = (uint4*)sWa;
        uint4* sB4 = (uint4*)sWb;
        for (int idx = (int)threadIdx.x; idx < 2048; idx += 256) {
            int n = idx >> 4, kc = idx & 15;
            int d = (n << 4) | (kc ^ (n & 15));
            sA4[d] = Wa4[idx];
            sB4[d] = Wb4[idx];
        }
    }

    float bva[8], bvb[8];
#pragma unroll
    for (int nt = 0; nt < 8; nt++) { bva[nt] = ba[nt * 16 + m]; bvb[nt] = bb[nt * 16 + m]; }

    bf16x8 wf[3][4];
    float fv0 = 0.f, fv1 = 0.f, fv2 = 0.f;
    bool valid2 = (m < 8);
    int obf = 0;
    if (DOFC) {
#pragma unroll
        for (int nt = 0; nt < 3; nt++) {
            const unsigned short* Bf = WfcT + (nt * 16 + m) * DF + quad * 8;
#pragma unroll
            for (int ks = 0; ks < 4; ks++) wf[nt][ks] = *(const bf16x8*)(Bf + ks * 32);
        }
        fv0 = bfc[m]; fv1 = bfc[16 + m];
        fv2 = valid2 ? bfc[32 + m] : 0.f;
        obf = flags[1];
    }
    __syncthreads();

    for (int tile = gw; tile < NNODES / 16; tile += MLP_WAVES) {
        int r0 = tile * 16;
        const unsigned short* Ab = A + (r0 + m) * DF + quad * 8;
        bf16x8 a[4];
#pragma unroll
        for (int ks = 0; ks < 4; ks++) a[ks] = *(const bf16x8*)(Ab + ks * 32);

        f32x4 acc[8];
#pragma unroll
        for (int nt = 0; nt < 8; nt++) acc[nt] = (f32x4){0.f, 0.f, 0.f, 0.f};
#pragma unroll
        for (int nt = 0; nt < 8; nt++) {
#pragma unroll
            for (int ks = 0; ks < 4; ks++) {
                bf16x8 w = *(const bf16x8*)&sWa[((nt * 16 + m) << 7) | ((((ks << 2) + quad) ^ m) << 3)];
                acc[nt] = __builtin_amdgcn_mfma_f32_16x16x32_bf16(a[ks], w, acc[nt], 0, 0, 0);
            }
        }

        // stage-1 epilogue -> per-wave tile (relu'd bf16), swizzled scalar writes
#pragma unroll
        for (int nt = 0; nt < 8; nt++)
#pragma unroll
            for (int reg = 0; reg < 4; reg++) {
                float v = acc[nt][reg] + bva[nt];
                if (v < 0.f) v = 0.f;
                int row = quad * 4 + reg, col = nt * 16 + m;
                T[(row << 7) | ((((col >> 3) ^ row) & 15) << 3) | (col & 7)] = f2bf(v);
            }

        // stage-2: A-frags from tile (row m), B-frags from sWb
        bf16x8 a2[4];
#pragma unroll
        for (int ks = 0; ks < 4; ks++)
            a2[ks] = *(const bf16x8*)&T[(m << 7) | ((((ks << 2) + quad) ^ m) << 3)];
#pragma unroll
        for (int nt = 0; nt < 8; nt++) acc[nt] = (f32x4){0.f, 0.f, 0.f, 0.f};
#pragma unroll
        for (int nt = 0; nt < 8; nt++) {
#pragma unroll
            for (int ks = 0; ks < 4; ks++) {
                bf16x8 w = *(const bf16x8*)&sWb[((nt * 16 + m) << 7) | ((((ks << 2) + quad) ^ m) << 3)];
                acc[nt] = __builtin_amdgcn_mfma_f32_16x16x32_bf16(a2[ks], w, acc[nt], 0, 0, 0);
            }
        }

        if (!DOFC) {
#pragma unroll
            for (int nt = 0; nt < 8; nt++) {
                int col = nt * 16 + m;
#pragma unroll
                for (int reg = 0; reg < 4; reg++) {
                    int row = r0 + quad * 4 + reg;
                    float v = acc[nt][reg] + bvb[nt];
                    if (v < 0.f) v = 0.f;
                    outH[row * DF + col] = f2bf(v);
                }
            }
        } else {
            // h2 -> tile (same-wave DS ops in-order after the a2 reads)
#pragma unroll
            for (int nt = 0; nt < 8; nt++)
#pragma unroll
                for (int reg = 0; reg < 4; reg++) {
                    float v = acc[nt][reg] + bvb[nt];
                    if (v < 0.f) v = 0.f;
                    int row = quad * 4 + reg, col = nt * 16 + m;
                    T[(row << 7) | ((((col >> 3) ^ row) & 15) << 3) | (col & 7)] = f2bf(v);
                }
            bf16x8 a3[4];
#pragma unroll
            for (int ks = 0; ks < 4; ks++)
                a3[ks] = *(const bf16x8*)&T[(m << 7) | ((((ks << 2) + quad) ^ m) << 3)];
            f32x4 fa[3];
#pragma unroll
            for (int nt = 0; nt < 3; nt++) fa[nt] = (f32x4){0.f, 0.f, 0.f, 0.f};
#pragma unroll
            for (int nt = 0; nt < 3; nt++)
#pragma unroll
                for (int ks = 0; ks < 4; ks++)
                    fa[nt] = __builtin_amdgcn_mfma_f32_16x16x32_bf16(a3[ks], wf[nt][ks], fa[nt], 0, 0, 0);

#pragma unroll
            for (int reg = 0; reg < 4; reg++) {
                float v0 = fa[0][reg] + fv0;
                float v1 = fa[1][reg] + fv1;
                float v2 = valid2 ? (fa[2][reg] + fv2) : -3.0e38f;
                float mx = fmaxf(fmaxf(v0, v1), v2);
#pragma unroll
                for (int off = 1; off < 16; off <<= 1) mx = fmaxf(mx, __shfl_xor(mx, off, 16));
                float e = __expf(v0 - mx) + __expf(v1 - mx) + (valid2 ? __expf(v2 - mx) : 0.f);
#pragma unroll
                for (int off = 1; off < 16; off <<= 1) e += __shfl_xor(e, off, 16);
                float l = mx + __logf(e);
                int row = r0 + quad * 4 + reg;
                if (obf) {
                    unsigned short* o = (unsigned short*)outFC + row * NC;
                    o[m] = f2bf(v0 - l);
                    o[16 + m] = f2bf(v1 - l);
                    if (valid2) o[32 + m] = f2bf(v2 - l);
                } else {
                    float* o = (float*)outFC + row * NC;
                    o[m] = v0 - l;
                    o[16 + m] = v1 - l;
                    if (valid2) o[32 + m] = v2 - l;
                }
            }
        }
    }
}

extern "C" void kernel_launch(void* const* d_in, const int* in_sizes, int n_in,
                              void* d_out, int out_size, void* d_ws, size_t ws_size,
                              hipStream_t stream) {
    const void* x   = d_in[0];
    const void* ei  = d_in[1];
    const void* w1a = d_in[2];
    const void* b1a = d_in[3];
    const void* w1b = d_in[4];
    const void* b1b = d_in[5];
    const void* w2a = d_in[6];
    const void* b2a = d_in[7];
    const void* w2b = d_in[8];
    const void* b2b = d_in[9];
    const void* wfc = d_in[10];
    const void* bfc = d_in[11];

    char* ws = (char*)d_ws;
    size_t off = 0;
    auto alloc = [&](size_t bytes) {
        void* p = ws + off;
        off += (bytes + 255) & ~(size_t)255;
        return p;
    };
    // B0/B1 have one extra zeroed row (ZROW) for the gather's slot clamp.
    unsigned short* B0    = (unsigned short*)alloc((size_t)(NNODES + 1) * DF * 2);
    unsigned short* B1    = (unsigned short*)alloc((size_t)(NNODES + 1) * DF * 2);
    int2*           ebin  = (int2*)alloc((size_t)NEDGES * 8);
    int*            perm  = (int*)alloc((size_t)(NEDGES + 64) * 4);   // +64 pad: slot over-read
    int*            rowptr= (int*)alloc((size_t)(NNODES + 1) * 4);
    int*            binCnt= (int*)alloc(NB * 4);
    int*            binOfs= (int*)alloc((NB + 1) * 4);
    int*            binCur= (int*)alloc(NB * 4);
    int*            flags = (int*)alloc(256);
    unsigned short* wAll  = (unsigned short*)alloc((4 * 16384 + NCP * 128) * 2);
    float*          bAll  = (float*)alloc((512 + NC) * 4);

    unsigned short* w1aT = wAll;
    unsigned short* w1bT = wAll + 16384;
    unsigned short* w2aT = wAll + 32768;
    unsigned short* w2bT = wAll + 49152;
    unsigned short* wfcT = wAll + 65536;
    float* b1af = bAll;
    float* b1bf = bAll + 128;
    float* b2af = bAll + 256;
    float* b2bf = bAll + 384;
    float* bfcf = bAll + 512;

    // ---- dtype detection (+ binCnt zero), then fused cvt + weight prep
    k_detect<<<1, 256, 0, stream>>>((const unsigned int*)ei, (const unsigned int*)x, flags, binCnt);
    int wprepN = 4 * 16384 + NCP * 128 + 512 + NC + 512;
    int prepGrid = CVT_BLOCKS + (wprepN + 255) / 256;
    k_prep<<<prepGrid, 256, 0, stream>>>(x, w1a, w1b, w2a, w2b, wfc,
                                         b1a, b1b, b2a, b2b, bfc,
                                         flags, B0, wAll, bAll,
                                         B0 + (size_t)NNODES * DF,
                                         B1 + (size_t)NNODES * DF);

    // ---- binned CSR build (reads edge_index directly)
    int nEB = (NEDGES + CH - 1) / CH;                          // 391
    k_bincount<<<nEB, 256, 0, stream>>>(ei, flags, binCnt);
    k_binscan<<<1, 256, 0, stream>>>(binCnt, binOfs, binCur);
    k_binscatter<<<nEB, 256, 0, stream>>>(ei, flags, binCur, ebin);
    k_binfill<<<NB, 256, 0, stream>>>(ebin, binOfs, rowptr, perm);

    const int gatherGrid = NNODES / 4;                         // 25000

    // ---- layer 1: gather -> fused MLP (h1 into B0; its ZROW pad stays zero)
    k_gather<<<gatherGrid, 256, 0, stream>>>(B0, B0, rowptr, perm, B1);
    k_mlp_lds<false><<<MLP_BLOCKS, 256, 0, stream>>>(B1, w1aT, b1af, w1bT, b1bf,
                                                     nullptr, nullptr, flags, B0, nullptr);

    // ---- layer 2: gather -> fused MLP + fc + log_softmax (h2 never hits global)
    k_gather<<<gatherGrid, 256, 0, stream>>>(B0, B0, rowptr, perm, B1);
    k_mlp_lds<true><<<MLP_BLOCKS, 256, 0, stream>>>(B1, w2aT, b2af, w2bT, b2bf,
                                                    wfcT, bfcf, flags, nullptr, d_out);
}

// Round 9
// 338.173 us; speedup vs baseline: 1.1829x; 1.1188x over previous
//
#include <hip/hip_runtime.h>
#include <hip/hip_bf16.h>

#define NNODES 100000
#define NEDGES 1600000
#define DF 128
#define NC 40
#define NCP 48          // padded fc cols (3 x 16)
#define NB 196          // CSR bins: dst>>9, 512 nodes/bin
#define CH 4096         // edges per binscatter/bincount block
#define MLP_BLOCKS 512  // fused MLP: 2 blocks/CU (80KB LDS each), 2 waves/SIMD
#define MLP_WAVES (MLP_BLOCKS * 4)
#define ZROW NNODES     // zero feature row appended to B0/B1
#define CVT_BLOCKS 6250 // NNODES*DF/(256*8)

typedef __bf16 bf16x8 __attribute__((ext_vector_type(8)));
typedef float f32x4 __attribute__((ext_vector_type(4)));
typedef float f32x2 __attribute__((ext_vector_type(2)));

__device__ __forceinline__ unsigned short f2bf(float f) {
    unsigned int u = __builtin_bit_cast(unsigned int, f);
    u = (u + 0x7FFFu + ((u >> 16) & 1u)) >> 16;   // RNE
    return (unsigned short)u;
}
__device__ __forceinline__ float bf2f(unsigned short s) {
    unsigned int u = ((unsigned int)s) << 16;
    return __builtin_bit_cast(float, u);
}
__device__ __forceinline__ float bfLo(unsigned int u) {
    return __builtin_bit_cast(float, u << 16);
}
__device__ __forceinline__ float bfHi(unsigned int u) {
    return __builtin_bit_cast(float, u & 0xFFFF0000u);
}
__device__ __forceinline__ f32x2 up2(unsigned int u) {
    return (f32x2){bfLo(u), bfHi(u)};
}

// ---------------- dtype detection (flags[0]: ei is int64; flags[1]: floats are bf16)
// also zeroes binCnt (fused memset).
__global__ void k_detect(const unsigned int* __restrict__ ei32,
                         const unsigned int* __restrict__ x32,
                         int* __restrict__ flags,
                         int* __restrict__ binCnt) {
    __shared__ unsigned int rOr[256];
    __shared__ int rCnt[256];
    for (int i = threadIdx.x; i < NB; i += 256) binCnt[i] = 0;
    unsigned int o = 0; int c = 0;
    for (int i = threadIdx.x; i < 1024; i += 256) o |= ei32[2 * i + 1];
    for (int i = threadIdx.x; i < 4096; i += 256) {
        unsigned int e = (x32[i] >> 7) & 0xFFu;
        c += (e >= 100u && e <= 140u) ? 1 : 0;
    }
    rOr[threadIdx.x] = o; rCnt[threadIdx.x] = c;
    __syncthreads();
    for (int s = 128; s; s >>= 1) {
        if ((int)threadIdx.x < s) {
            rOr[threadIdx.x] |= rOr[threadIdx.x + s];
            rCnt[threadIdx.x] += rCnt[threadIdx.x + s];
        }
        __syncthreads();
    }
    if (threadIdx.x == 0) {
        flags[0] = (rOr[0] == 0u) ? 1 : 0;
        flags[1] = (rCnt[0] > 2457) ? 1 : 0;
    }
}

__device__ __forceinline__ int ldIdx(const void* ei, int flag64, int i) {
    return flag64 ? (int)((const long long*)ei)[i] : ((const int*)ei)[i];
}

// ---------------- fused prep: feature cvt (blocks < CVT_BLOCKS) + weight/bias
// transposes + zero-row pads (remaining blocks). One dispatch.
__global__ __launch_bounds__(256) void k_prep(const void* __restrict__ src,
                                              const void* w1a, const void* w1b,
                                              const void* w2a, const void* w2b,
                                              const void* wfc,
                                              const void* b1a, const void* b1b,
                                              const void* b2a, const void* b2b,
                                              const void* bfc,
                                              const int* __restrict__ flags,
                                              unsigned short* __restrict__ dst,
                                              unsigned short* __restrict__ wAll,
                                              float* __restrict__ bAll,
                                              unsigned short* __restrict__ pad0,
                                              unsigned short* __restrict__ pad1) {
    int bf = flags[1];
    if (blockIdx.x < CVT_BLOCKS) {
        int i = blockIdx.x * 256 + threadIdx.x;   // 8 bf16 elems each
        if (bf) {
            ((uint4*)dst)[i] = ((const uint4*)src)[i];
        } else {
            uint4 a = ((const uint4*)src)[2 * i];
            uint4 b = ((const uint4*)src)[2 * i + 1];
            auto pk = [](unsigned int lo, unsigned int hi) -> unsigned int {
                return ((unsigned int)f2bf(__builtin_bit_cast(float, hi)) << 16) |
                       f2bf(__builtin_bit_cast(float, lo));
            };
            uint4 r;
            r.x = pk(a.x, a.y);
            r.y = pk(a.z, a.w);
            r.z = pk(b.x, b.y);
            r.w = pk(b.z, b.w);
            ((uint4*)dst)[i] = r;
        }
        return;
    }
    int idx = (blockIdx.x - CVT_BLOCKS) * 256 + threadIdx.x;
    auto ldf = [&](const void* p, int i) -> float {
        return bf ? bf2f(((const unsigned short*)p)[i]) : ((const float*)p)[i];
    };
    if (idx < 65536) {                       // 4 square transposes
        int wi = idx >> 14, r = idx & 16383;
        int n = r >> 7, k = r & 127;
        const void* s = (wi == 0) ? w1a : (wi == 1) ? w1b : (wi == 2) ? w2a : w2b;
        wAll[idx] = f2bf(ldf(s, k * 128 + n));
    } else if (idx < 65536 + NCP * 128) {    // wfc transpose, zero pad
        int r = idx - 65536;
        int n = r >> 7, k = r & 127;
        wAll[idx] = (n < NC) ? f2bf(ldf(wfc, k * NC + n)) : (unsigned short)0;
    } else if (idx < 65536 + NCP * 128 + 512 + NC) {
        int r = idx - (65536 + NCP * 128);
        const void* s; int i;
        if (r < 128)      { s = b1a; i = r; }
        else if (r < 256) { s = b1b; i = r - 128; }
        else if (r < 384) { s = b2a; i = r - 256; }
        else if (r < 512) { s = b2b; i = r - 384; }
        else              { s = bfc; i = r - 512; }
        bAll[r] = ldf(s, i);
    } else if (idx < 65536 + NCP * 128 + 512 + NC + 256) {
        pad0[idx - (65536 + NCP * 128 + 512 + NC)] = 0;   // B0 zero row
    } else if (idx < 65536 + NCP * 128 + 512 + NC + 512) {
        pad1[idx - (65536 + NCP * 128 + 512 + NC + 256)] = 0;  // B1 zero row
    }
}

// ================= binned CSR build =================
__global__ __launch_bounds__(256) void k_bincount(const void* __restrict__ ei,
                                                  const int* __restrict__ flags,
                                                  int* __restrict__ binCnt) {
    __shared__ int l[NB];
    int t = threadIdx.x;
    int f64 = flags[0];
    for (int i = t; i < NB; i += 256) l[i] = 0;
    __syncthreads();
    int base = blockIdx.x * CH;
#pragma unroll
    for (int k = 0; k < CH / 256; k++) {
        int e = base + k * 256 + t;
        if (e < NEDGES) atomicAdd(&l[ldIdx(ei, f64, NEDGES + e) >> 9], 1);
    }
    __syncthreads();
    for (int i = t; i < NB; i += 256)
        if (l[i]) atomicAdd(&binCnt[i], l[i]);
}

__global__ __launch_bounds__(256) void k_binscan(const int* __restrict__ binCnt,
                                                 int* __restrict__ binOfs,
                                                 int* __restrict__ binCur) {
    __shared__ int sh[256];
    int t = threadIdx.x;
    int v = (t < NB) ? binCnt[t] : 0;
    sh[t] = v;
    __syncthreads();
    for (int off = 1; off < 256; off <<= 1) {
        int x = (t >= off) ? sh[t - off] : 0;
        __syncthreads();
        sh[t] += x;
        __syncthreads();
    }
    if (t < NB) {
        binOfs[t + 1] = sh[t];
        binCur[t] = sh[t] - v;      // exclusive
    }
    if (t == 0) binOfs[0] = 0;
}

__global__ __launch_bounds__(256) void k_binscatter(const void* __restrict__ ei,
                                                    const int* __restrict__ flags,
                                                    int* __restrict__ binCur,
                                                    int2* __restrict__ ebin) {
    __shared__ int lcnt[NB], lbase[NB], lofs[NB];
    int t = threadIdx.x;
    int f64 = flags[0];
    for (int i = t; i < NB; i += 256) lcnt[i] = 0;
    __syncthreads();
    int base = blockIdx.x * CH;
    int2 ed[CH / 256];
    int bn[CH / 256];
#pragma unroll
    for (int k = 0; k < CH / 256; k++) {
        int e = base + k * 256 + t;
        if (e < NEDGES) {
            ed[k].x = ldIdx(ei, f64, e);
            ed[k].y = ldIdx(ei, f64, NEDGES + e);
            bn[k] = ed[k].y >> 9;
            atomicAdd(&lcnt[bn[k]], 1);
        } else bn[k] = -1;
    }
    __syncthreads();
    if (t < NB) {
        int c = lcnt[t];
        lbase[t] = c ? atomicAdd(&binCur[t], c) : 0;
        lofs[t] = 0;
    }
    __syncthreads();
#pragma unroll
    for (int k = 0; k < CH / 256; k++) {
        if (bn[k] >= 0) {
            int p = lbase[bn[k]] + atomicAdd(&lofs[bn[k]], 1);
            ebin[p] = ed[k];
        }
    }
}

__global__ __launch_bounds__(256) void k_binfill(const int2* __restrict__ ebin,
                                                 const int* __restrict__ binOfs,
                                                 int* __restrict__ rowptr,
                                                 int* __restrict__ perm) {
    __shared__ int deg[512], lptr[512], ssum[256];
    int b = blockIdx.x, t = threadIdx.x;
    int n0 = b << 9;
    int nn = NNODES - n0; if (nn > 512) nn = 512;
    int e0 = binOfs[b], e1 = binOfs[b + 1];
    deg[t] = 0; deg[t + 256] = 0;
    __syncthreads();
    for (int e = e0 + t; e < e1; e += 256)
        atomicAdd(&deg[ebin[e].y - n0], 1);
    __syncthreads();
    int d0 = deg[2 * t], d1 = deg[2 * t + 1];
    int s = d0 + d1;
    ssum[t] = s;
    __syncthreads();
    for (int off = 1; off < 256; off <<= 1) {
        int x = (t >= off) ? ssum[t - off] : 0;
        __syncthreads();
        ssum[t] += x;
        __syncthreads();
    }
    int ex = ssum[t] - s;
    lptr[2 * t] = ex;
    lptr[2 * t + 1] = ex + d0;
    if (2 * t < nn)     rowptr[n0 + 2 * t] = e0 + ex;
    if (2 * t + 1 < nn) rowptr[n0 + 2 * t + 1] = e0 + ex + d0;
    if (b == NB - 1 && t == 0) rowptr[NNODES] = e1;
    deg[2 * t] = 0; deg[2 * t + 1] = 0;   // reuse as cursor
    __syncthreads();
    for (int e = e0 + t; e < e1; e += 256) {
        int2 ed = ebin[e];
        int d = ed.y - n0;
        int pos = e0 + lptr[d] + atomicAdd(&deg[d], 1);
        perm[pos] = ed.x;
    }
}

// ================= gather aggregation (R4 best: 57.0us, at pattern ceiling) ==
__device__ __forceinline__ void accu(f32x2* acc, uint4 u) {
    acc[0] += up2(u.x);
    acc[1] += up2(u.y);
    acc[2] += up2(u.z);
    acc[3] += up2(u.w);
}

template <int S>
__device__ __forceinline__ void gslots(const int* __restrict__ perm, const uint4* __restrict__ F,
                                       int j, int je, int g, int c, f32x2* acc) {
    int pm[S];
#pragma unroll
    for (int k = 0; k < S; k++) pm[k] = perm[j + 4 * k + g];
#pragma unroll
    for (int k = 0; k < S; k++)
        if (j + 4 * k + g >= je) pm[k] = ZROW;       // value-clamp, off the addr-issue path
    uint4 u[S];
#pragma unroll
    for (int k = 0; k < S; k++) u[k] = F[pm[k] * 16 + c];
#pragma unroll
    for (int k = 0; k < S; k++) accu(acc, u[k]);
}

__global__ __launch_bounds__(256) void k_gather(const unsigned short* __restrict__ feat,
                                                const unsigned short* __restrict__ x,
                                                const int* __restrict__ rowptr,
                                                const int* __restrict__ perm,
                                                unsigned short* __restrict__ out) {
    int wave = threadIdx.x >> 6, lane = threadIdx.x & 63;
    int i = blockIdx.x * 4 + wave;        // NNODES = 25000*4 exactly
    int g = lane >> 4, c = lane & 15;
    const uint4* F = (const uint4*)feat;  // one row = 16 uint4

    uint4 xv = ((const uint4*)x)[i * 16 + c];
    int jb = rowptr[i], je = rowptr[i + 1];

    f32x2 acc[4];
#pragma unroll
    for (int k = 0; k < 4; k++) acc[k] = (f32x2){0.f, 0.f};

    int j = jb;
    while (je - j > 24) {
        int s0 = perm[j + g], s1 = perm[j + 4 + g];
        int s2 = perm[j + 8 + g], s3 = perm[j + 12 + g];
        uint4 u0 = F[s0 * 16 + c];
        uint4 u1 = F[s1 * 16 + c];
        uint4 u2 = F[s2 * 16 + c];
        uint4 u3 = F[s3 * 16 + c];
        accu(acc, u0); accu(acc, u1); accu(acc, u2); accu(acc, u3);
        j += 16;
    }
    int deg = je - j;                     // 0..24, wave-uniform
    if (deg > 16)      gslots<6>(perm, F, j, je, g, c, acc);
    else if (deg > 8)  gslots<4>(perm, F, j, je, g, c, acc);
    else if (deg > 0)  gslots<2>(perm, F, j, je, g, c, acc);

#pragma unroll
    for (int k = 0; k < 4; k++) {
        acc[k][0] += __shfl_xor(acc[k][0], 16);
        acc[k][1] += __shfl_xor(acc[k][1], 16);
        acc[k][0] += __shfl_xor(acc[k][0], 32);
        acc[k][1] += __shfl_xor(acc[k][1], 32);
    }

    acc[0] += up2(xv.x);
    acc[1] += up2(xv.y);
    acc[2] += up2(xv.z);
    acc[3] += up2(xv.w);

    if (g == 0) {
        uint4 r;
        r.x = ((unsigned int)f2bf(acc[0][1]) << 16) | f2bf(acc[0][0]);
        r.y = ((unsigned int)f2bf(acc[1][1]) << 16) | f2bf(acc[1][0]);
        r.z = ((unsigned int)f2bf(acc[2][1]) << 16) | f2bf(acc[2][0]);
        r.w = ((unsigned int)f2bf(acc[3][1]) << 16) | f2bf(acc[3][0]);
        ((uint4*)out)[i * 16 + c] = r;
    }
}

// ================= fused GIN MLP v4: out = relu(relu(A@Wa+ba)@Wb+bb) ==========
// R8 post-mortem: excess traffic (+79MB rd / +60MB wr) was NOT spill (R7/R8
// identical traffic, different reg structure) — it's the scattered u16
// epilogue: 32B partial writes per L2 line -> RFO fetch + multiple partial
// dirty evictions under A-stream pressure (3.3x write amp). v4 routes the
// final result through the per-wave sT tile, then stores with lane mapping
// (r2=lane>>3, c8=lane&7): each of 4 dwordx4 store instrs writes 8 rows x
// 128B contiguous = 8 FULL L2 lines. Zero partials, zero RFO.
// Weights in swizzled LDS as R8 (proven correct). LDS 80KB, 2 blocks/CU.
template <bool DOFC>
__global__ __launch_bounds__(256, 2) void k_mlp_lds(const unsigned short* __restrict__ A,
                                                    const unsigned short* __restrict__ WaT,
                                                    const float* __restrict__ ba,
                                                    const unsigned short* __restrict__ WbT,
                                                    const float* __restrict__ bb,
                                                    const unsigned short* __restrict__ WfcT,
                                                    const float* __restrict__ bfc,
                                                    const int* __restrict__ flags,
                                                    unsigned short* __restrict__ outH,
                                                    void* __restrict__ outFC) {
    __shared__ __align__(16) unsigned short sWa[16384];   // 128x128 swizzled
    __shared__ __align__(16) unsigned short sWb[16384];   // 128x128 swizzled
    __shared__ __align__(16) unsigned short sT[4][2048];  // per-wave 16x128 swizzled

    int wave = threadIdx.x >> 6, lane = threadIdx.x & 63;
    int gw = blockIdx.x * 4 + wave;
    int m = lane & 15, quad = lane >> 4;
    unsigned short* T = sT[wave];

    // stage Wa+Wb into swizzled LDS: 16B-chunk permutation -> uint4 copies
    {
        const uint4* Wa4 = (const uint4*)WaT;
        const uint4* Wb4 = (const uint4*)WbT;
        uint4* sA4 = (uint4*)sWa;
        uint4* sB4 = (uint4*)sWb;
        for (int idx = (int)threadIdx.x; idx < 2048; idx += 256) {
            int n = idx >> 4, kc = idx & 15;
            int d = (n << 4) | (kc ^ (n & 15));
            sA4[d] = Wa4[idx];
            sB4[d] = Wb4[idx];
        }
    }

    float bva[8], bvb[8];
#pragma unroll
    for (int nt = 0; nt < 8; nt++) { bva[nt] = ba[nt * 16 + m]; bvb[nt] = bb[nt * 16 + m]; }

    bf16x8 wf[3][4];
    float fv0 = 0.f, fv1 = 0.f, fv2 = 0.f;
    bool valid2 = (m < 8);
    int obf = 0;
    if (DOFC) {
#pragma unroll
        for (int nt = 0; nt < 3; nt++) {
            const unsigned short* Bf = WfcT + (nt * 16 + m) * DF + quad * 8;
#pragma unroll
            for (int ks = 0; ks < 4; ks++) wf[nt][ks] = *(const bf16x8*)(Bf + ks * 32);
        }
        fv0 = bfc[m]; fv1 = bfc[16 + m];
        fv2 = valid2 ? bfc[32 + m] : 0.f;
        obf = flags[1];
    }
    __syncthreads();

    for (int tile = gw; tile < NNODES / 16; tile += MLP_WAVES) {
        int r0 = tile * 16;
        const unsigned short* Ab = A + (r0 + m) * DF + quad * 8;
        bf16x8 a[4];
#pragma unroll
        for (int ks = 0; ks < 4; ks++) a[ks] = *(const bf16x8*)(Ab + ks * 32);

        f32x4 acc[8];
#pragma unroll
        for (int nt = 0; nt < 8; nt++) acc[nt] = (f32x4){0.f, 0.f, 0.f, 0.f};
#pragma unroll
        for (int nt = 0; nt < 8; nt++) {
#pragma unroll
            for (int ks = 0; ks < 4; ks++) {
                bf16x8 w = *(const bf16x8*)&sWa[((nt * 16 + m) << 7) | ((((ks << 2) + quad) ^ m) << 3)];
                acc[nt] = __builtin_amdgcn_mfma_f32_16x16x32_bf16(a[ks], w, acc[nt], 0, 0, 0);
            }
        }

        // stage-1 epilogue -> per-wave tile (relu'd bf16), swizzled scalar writes
#pragma unroll
        for (int nt = 0; nt < 8; nt++)
#pragma unroll
            for (int reg = 0; reg < 4; reg++) {
                float v = acc[nt][reg] + bva[nt];
                if (v < 0.f) v = 0.f;
                int row = quad * 4 + reg, col = nt * 16 + m;
                T[(row << 7) | ((((col >> 3) ^ row) & 15) << 3) | (col & 7)] = f2bf(v);
            }

        // stage-2: A-frags from tile (row m), B-frags from sWb
        bf16x8 a2[4];
#pragma unroll
        for (int ks = 0; ks < 4; ks++)
            a2[ks] = *(const bf16x8*)&T[(m << 7) | ((((ks << 2) + quad) ^ m) << 3)];
#pragma unroll
        for (int nt = 0; nt < 8; nt++) acc[nt] = (f32x4){0.f, 0.f, 0.f, 0.f};
#pragma unroll
        for (int nt = 0; nt < 8; nt++) {
#pragma unroll
            for (int ks = 0; ks < 4; ks++) {
                bf16x8 w = *(const bf16x8*)&sWb[((nt * 16 + m) << 7) | ((((ks << 2) + quad) ^ m) << 3)];
                acc[nt] = __builtin_amdgcn_mfma_f32_16x16x32_bf16(a2[ks], w, acc[nt], 0, 0, 0);
            }
        }

        if (!DOFC) {
            // h -> tile (same swizzle; same-wave DS in-order after a2 reads)
#pragma unroll
            for (int nt = 0; nt < 8; nt++)
#pragma unroll
                for (int reg = 0; reg < 4; reg++) {
                    float v = acc[nt][reg] + bvb[nt];
                    if (v < 0.f) v = 0.f;
                    int row = quad * 4 + reg, col = nt * 16 + m;
                    T[(row << 7) | ((((col >> 3) ^ row) & 15) << 3) | (col & 7)] = f2bf(v);
                }
            // full-line vectorized store: 4 instrs x 8 rows x 128B full lines
            int r2 = lane >> 3, c8 = lane & 7;
            const uint4* T4 = (const uint4*)T;
            uint4* O4 = (uint4*)(outH + (size_t)r0 * DF);
#pragma unroll
            for (int half = 0; half < 2; half++) {
                int row = r2 + half * 8;
#pragma unroll
                for (int lin = 0; lin < 2; lin++) {
                    int ch = c8 + lin * 8;
                    uint4 v = T4[(row << 4) | (ch ^ row)];
                    O4[row * 16 + ch] = v;
                }
            }
        } else {
            // h2 -> tile (same-wave DS ops in-order after the a2 reads)
#pragma unroll
            for (int nt = 0; nt < 8; nt++)
#pragma unroll
                for (int reg = 0; reg < 4; reg++) {
                    float v = acc[nt][reg] + bvb[nt];
                    if (v < 0.f) v = 0.f;
                    int row = quad * 4 + reg, col = nt * 16 + m;
                    T[(row << 7) | ((((col >> 3) ^ row) & 15) << 3) | (col & 7)] = f2bf(v);
                }
            bf16x8 a3[4];
#pragma unroll
            for (int ks = 0; ks < 4; ks++)
                a3[ks] = *(const bf16x8*)&T[(m << 7) | ((((ks << 2) + quad) ^ m) << 3)];
            f32x4 fa[3];
#pragma unroll
            for (int nt = 0; nt < 3; nt++) fa[nt] = (f32x4){0.f, 0.f, 0.f, 0.f};
#pragma unroll
            for (int nt = 0; nt < 3; nt++)
#pragma unroll
                for (int ks = 0; ks < 4; ks++)
                    fa[nt] = __builtin_amdgcn_mfma_f32_16x16x32_bf16(a3[ks], wf[nt][ks], fa[nt], 0, 0, 0);

#pragma unroll
            for (int reg = 0; reg < 4; reg++) {
                float v0 = fa[0][reg] + fv0;
                float v1 = fa[1][reg] + fv1;
                float v2 = valid2 ? (fa[2][reg] + fv2) : -3.0e38f;
                float mx = fmaxf(fmaxf(v0, v1), v2);
#pragma unroll
                for (int off = 1; off < 16; off <<= 1) mx = fmaxf(mx, __shfl_xor(mx, off, 16));
                float e = __expf(v0 - mx) + __expf(v1 - mx) + (valid2 ? __expf(v2 - mx) : 0.f);
#pragma unroll
                for (int off = 1; off < 16; off <<= 1) e += __shfl_xor(e, off, 16);
                float l = mx + __logf(e);
                int row = r0 + quad * 4 + reg;
                if (obf) {
                    unsigned short* o = (unsigned short*)outFC + row * NC;
                    o[m] = f2bf(v0 - l);
                    o[16 + m] = f2bf(v1 - l);
                    if (valid2) o[32 + m] = f2bf(v2 - l);
                } else {
                    float* o = (float*)outFC + row * NC;
                    o[m] = v0 - l;
                    o[16 + m] = v1 - l;
                    if (valid2) o[32 + m] = v2 - l;
                }
            }
        }
    }
}

extern "C" void kernel_launch(void* const* d_in, const int* in_sizes, int n_in,
                              void* d_out, int out_size, void* d_ws, size_t ws_size,
                              hipStream_t stream) {
    const void* x   = d_in[0];
    const void* ei  = d_in[1];
    const void* w1a = d_in[2];
    const void* b1a = d_in[3];
    const void* w1b = d_in[4];
    const void* b1b = d_in[5];
    const void* w2a = d_in[6];
    const void* b2a = d_in[7];
    const void* w2b = d_in[8];
    const void* b2b = d_in[9];
    const void* wfc = d_in[10];
    const void* bfc = d_in[11];

    char* ws = (char*)d_ws;
    size_t off = 0;
    auto alloc = [&](size_t bytes) {
        void* p = ws + off;
        off += (bytes + 255) & ~(size_t)255;
        return p;
    };
    // B0/B1 have one extra zeroed row (ZROW) for the gather's slot clamp.
    unsigned short* B0    = (unsigned short*)alloc((size_t)(NNODES + 1) * DF * 2);
    unsigned short* B1    = (unsigned short*)alloc((size_t)(NNODES + 1) * DF * 2);
    int2*           ebin  = (int2*)alloc((size_t)NEDGES * 8);
    int*            perm  = (int*)alloc((size_t)(NEDGES + 64) * 4);   // +64 pad: slot over-read
    int*            rowptr= (int*)alloc((size_t)(NNODES + 1) * 4);
    int*            binCnt= (int*)alloc(NB * 4);
    int*            binOfs= (int*)alloc((NB + 1) * 4);
    int*            binCur= (int*)alloc(NB * 4);
    int*            flags = (int*)alloc(256);
    unsigned short* wAll  = (unsigned short*)alloc((4 * 16384 + NCP * 128) * 2);
    float*          bAll  = (float*)alloc((512 + NC) * 4);

    unsigned short* w1aT = wAll;
    unsigned short* w1bT = wAll + 16384;
    unsigned short* w2aT = wAll + 32768;
    unsigned short* w2bT = wAll + 49152;
    unsigned short* wfcT = wAll + 65536;
    float* b1af = bAll;
    float* b1bf = bAll + 128;
    float* b2af = bAll + 256;
    float* b2bf = bAll + 384;
    float* bfcf = bAll + 512;

    // ---- dtype detection (+ binCnt zero), then fused cvt + weight prep
    k_detect<<<1, 256, 0, stream>>>((const unsigned int*)ei, (const unsigned int*)x, flags, binCnt);
    int wprepN = 4 * 16384 + NCP * 128 + 512 + NC + 512;
    int prepGrid = CVT_BLOCKS + (wprepN + 255) / 256;
    k_prep<<<prepGrid, 256, 0, stream>>>(x, w1a, w1b, w2a, w2b, wfc,
                                         b1a, b1b, b2a, b2b, bfc,
                                         flags, B0, wAll, bAll,
                                         B0 + (size_t)NNODES * DF,
                                         B1 + (size_t)NNODES * DF);

    // ---- binned CSR build (reads edge_index directly)
    int nEB = (NEDGES + CH - 1) / CH;                          // 391
    k_bincount<<<nEB, 256, 0, stream>>>(ei, flags, binCnt);
    k_binscan<<<1, 256, 0, stream>>>(binCnt, binOfs, binCur);
    k_binscatter<<<nEB, 256, 0, stream>>>(ei, flags, binCur, ebin);
    k_binfill<<<NB, 256, 0, stream>>>(ebin, binOfs, rowptr, perm);

    const int gatherGrid = NNODES / 4;                         // 25000

    // ---- layer 1: gather -> fused MLP (h1 into B0; its ZROW pad stays zero)
    k_gather<<<gatherGrid, 256, 0, stream>>>(B0, B0, rowptr, perm, B1);
    k_mlp_lds<false><<<MLP_BLOCKS, 256, 0, stream>>>(B1, w1aT, b1af, w1bT, b1bf,
                                                     nullptr, nullptr, flags, B0, nullptr);

    // ---- layer 2: gather -> fused MLP + fc + log_softmax (h2 never hits global)
    k_gather<<<gatherGrid, 256, 0, stream>>>(B0, B0, rowptr, perm, B1);
    k_mlp_lds<true><<<MLP_BLOCKS, 256, 0, stream>>>(B1, w2aT, b2af, w2bT, b2bf,
                                                    wfcT, bfcf, flags, nullptr, d_out);
}

// Round 10
// 336.426 us; speedup vs baseline: 1.1890x; 1.0052x over previous
//
#include <hip/hip_runtime.h>
#include <hip/hip_bf16.h>

#define NNODES 100000
#define NEDGES 1600000
#define DF 128
#define NC 40
#define NCP 48          // padded fc cols (3 x 16)
#define NB 196          // CSR bins: dst>>9, 512 nodes/bin
#define CH 4096         // edges per binscatter/bincount block
#define MLP_BLOCKS 512  // fused MLP: 2 blocks/CU (80KB LDS each), 2 waves/SIMD
#define MLP_WAVES (MLP_BLOCKS * 4)
#define ZROW NNODES     // zero feature row appended to B0/B1
#define CVT_BLOCKS 6250 // NNODES*DF/(256*8)
#define WPREP_N (4 * 16384 + NCP * 128 + 512 + NC + 512)
#define WPREP_BLOCKS ((WPREP_N + 255) / 256)
#define NEB ((NEDGES + CH - 1) / CH)   // 391

typedef __bf16 bf16x8 __attribute__((ext_vector_type(8)));
typedef float f32x4 __attribute__((ext_vector_type(4)));
typedef float f32x2 __attribute__((ext_vector_type(2)));

__device__ __forceinline__ unsigned short f2bf(float f) {
    unsigned int u = __builtin_bit_cast(unsigned int, f);
    u = (u + 0x7FFFu + ((u >> 16) & 1u)) >> 16;   // RNE
    return (unsigned short)u;
}
__device__ __forceinline__ float bf2f(unsigned short s) {
    unsigned int u = ((unsigned int)s) << 16;
    return __builtin_bit_cast(float, u);
}
__device__ __forceinline__ float bfLo(unsigned int u) {
    return __builtin_bit_cast(float, u << 16);
}
__device__ __forceinline__ float bfHi(unsigned int u) {
    return __builtin_bit_cast(float, u & 0xFFFF0000u);
}
__device__ __forceinline__ f32x2 up2(unsigned int u) {
    return (f32x2){bfLo(u), bfHi(u)};
}

// ---------------- dtype detection (flags[0]: ei is int64; flags[1]: floats are bf16)
// also zeroes binCnt (fused memset).
__global__ void k_detect(const unsigned int* __restrict__ ei32,
                         const unsigned int* __restrict__ x32,
                         int* __restrict__ flags,
                         int* __restrict__ binCnt) {
    __shared__ unsigned int rOr[256];
    __shared__ int rCnt[256];
    for (int i = threadIdx.x; i < NB; i += 256) binCnt[i] = 0;
    unsigned int o = 0; int c = 0;
    for (int i = threadIdx.x; i < 1024; i += 256) o |= ei32[2 * i + 1];
    for (int i = threadIdx.x; i < 4096; i += 256) {
        unsigned int e = (x32[i] >> 7) & 0xFFu;
        c += (e >= 100u && e <= 140u) ? 1 : 0;
    }
    rOr[threadIdx.x] = o; rCnt[threadIdx.x] = c;
    __syncthreads();
    for (int s = 128; s; s >>= 1) {
        if ((int)threadIdx.x < s) {
            rOr[threadIdx.x] |= rOr[threadIdx.x + s];
            rCnt[threadIdx.x] += rCnt[threadIdx.x + s];
        }
        __syncthreads();
    }
    if (threadIdx.x == 0) {
        flags[0] = (rOr[0] == 0u) ? 1 : 0;
        flags[1] = (rCnt[0] > 2457) ? 1 : 0;
    }
}

__device__ __forceinline__ int ldIdx(const void* ei, int flag64, int i) {
    return flag64 ? (int)((const long long*)ei)[i] : ((const int*)ei)[i];
}

// ---------------- fused prep: feature cvt + weight/bias transposes + zero-row
// pads + bincount (third grid partition; both depend only on flags). One dispatch.
__global__ __launch_bounds__(256) void k_prep(const void* __restrict__ src,
                                              const void* w1a, const void* w1b,
                                              const void* w2a, const void* w2b,
                                              const void* wfc,
                                              const void* b1a, const void* b1b,
                                              const void* b2a, const void* b2b,
                                              const void* bfc,
                                              const void* __restrict__ ei,
                                              const int* __restrict__ flags,
                                              unsigned short* __restrict__ dst,
                                              unsigned short* __restrict__ wAll,
                                              float* __restrict__ bAll,
                                              unsigned short* __restrict__ pad0,
                                              unsigned short* __restrict__ pad1,
                                              int* __restrict__ binCnt) {
    int bf = flags[1];
    if (blockIdx.x < CVT_BLOCKS) {
        int i = blockIdx.x * 256 + threadIdx.x;   // 8 bf16 elems each
        if (bf) {
            ((uint4*)dst)[i] = ((const uint4*)src)[i];
        } else {
            uint4 a = ((const uint4*)src)[2 * i];
            uint4 b = ((const uint4*)src)[2 * i + 1];
            auto pk = [](unsigned int lo, unsigned int hi) -> unsigned int {
                return ((unsigned int)f2bf(__builtin_bit_cast(float, hi)) << 16) |
                       f2bf(__builtin_bit_cast(float, lo));
            };
            uint4 r;
            r.x = pk(a.x, a.y);
            r.y = pk(a.z, a.w);
            r.z = pk(b.x, b.y);
            r.w = pk(b.z, b.w);
            ((uint4*)dst)[i] = r;
        }
        return;
    }
    if (blockIdx.x >= CVT_BLOCKS + WPREP_BLOCKS) {
        // -------- bincount partition --------
        __shared__ int l[NB];
        int t = threadIdx.x;
        int f64 = flags[0];
        for (int i = t; i < NB; i += 256) l[i] = 0;
        __syncthreads();
        int base = (blockIdx.x - CVT_BLOCKS - WPREP_BLOCKS) * CH;
#pragma unroll
        for (int k = 0; k < CH / 256; k++) {
            int e = base + k * 256 + t;
            if (e < NEDGES) atomicAdd(&l[ldIdx(ei, f64, NEDGES + e) >> 9], 1);
        }
        __syncthreads();
        for (int i = t; i < NB; i += 256)
            if (l[i]) atomicAdd(&binCnt[i], l[i]);
        return;
    }
    int idx = (blockIdx.x - CVT_BLOCKS) * 256 + threadIdx.x;
    auto ldf = [&](const void* p, int i) -> float {
        return bf ? bf2f(((const unsigned short*)p)[i]) : ((const float*)p)[i];
    };
    if (idx < 65536) {                       // 4 square transposes
        int wi = idx >> 14, r = idx & 16383;
        int n = r >> 7, k = r & 127;
        const void* s = (wi == 0) ? w1a : (wi == 1) ? w1b : (wi == 2) ? w2a : w2b;
        wAll[idx] = f2bf(ldf(s, k * 128 + n));
    } else if (idx < 65536 + NCP * 128) {    // wfc transpose, zero pad
        int r = idx - 65536;
        int n = r >> 7, k = r & 127;
        wAll[idx] = (n < NC) ? f2bf(ldf(wfc, k * NC + n)) : (unsigned short)0;
    } else if (idx < 65536 + NCP * 128 + 512 + NC) {
        int r = idx - (65536 + NCP * 128);
        const void* s; int i;
        if (r < 128)      { s = b1a; i = r; }
        else if (r < 256) { s = b1b; i = r - 128; }
        else if (r < 384) { s = b2a; i = r - 256; }
        else if (r < 512) { s = b2b; i = r - 384; }
        else              { s = bfc; i = r - 512; }
        bAll[r] = ldf(s, i);
    } else if (idx < 65536 + NCP * 128 + 512 + NC + 256) {
        pad0[idx - (65536 + NCP * 128 + 512 + NC)] = 0;   // B0 zero row
    } else if (idx < 65536 + NCP * 128 + 512 + NC + 512) {
        pad1[idx - (65536 + NCP * 128 + 512 + NC + 256)] = 0;  // B1 zero row
    }
}

// ================= binned CSR build (scan / scatter / fill) =================
__global__ __launch_bounds__(256) void k_binscan(const int* __restrict__ binCnt,
                                                 int* __restrict__ binOfs,
                                                 int* __restrict__ binCur) {
    __shared__ int sh[256];
    int t = threadIdx.x;
    int v = (t < NB) ? binCnt[t] : 0;
    sh[t] = v;
    __syncthreads();
    for (int off = 1; off < 256; off <<= 1) {
        int x = (t >= off) ? sh[t - off] : 0;
        __syncthreads();
        sh[t] += x;
        __syncthreads();
    }
    if (t < NB) {
        binOfs[t + 1] = sh[t];
        binCur[t] = sh[t] - v;      // exclusive
    }
    if (t == 0) binOfs[0] = 0;
}

__global__ __launch_bounds__(256) void k_binscatter(const void* __restrict__ ei,
                                                    const int* __restrict__ flags,
                                                    int* __restrict__ binCur,
                                                    int2* __restrict__ ebin) {
    __shared__ int lcnt[NB], lbase[NB], lofs[NB];
    int t = threadIdx.x;
    int f64 = flags[0];
    for (int i = t; i < NB; i += 256) lcnt[i] = 0;
    __syncthreads();
    int base = blockIdx.x * CH;
    int2 ed[CH / 256];
    int bn[CH / 256];
#pragma unroll
    for (int k = 0; k < CH / 256; k++) {
        int e = base + k * 256 + t;
        if (e < NEDGES) {
            ed[k].x = ldIdx(ei, f64, e);
            ed[k].y = ldIdx(ei, f64, NEDGES + e);
            bn[k] = ed[k].y >> 9;
            atomicAdd(&lcnt[bn[k]], 1);
        } else bn[k] = -1;
    }
    __syncthreads();
    if (t < NB) {
        int c = lcnt[t];
        lbase[t] = c ? atomicAdd(&binCur[t], c) : 0;
        lofs[t] = 0;
    }
    __syncthreads();
#pragma unroll
    for (int k = 0; k < CH / 256; k++) {
        if (bn[k] >= 0) {
            int p = lbase[bn[k]] + atomicAdd(&lofs[bn[k]], 1);
            ebin[p] = ed[k];
        }
    }
}

__global__ __launch_bounds__(256) void k_binfill(const int2* __restrict__ ebin,
                                                 const int* __restrict__ binOfs,
                                                 int* __restrict__ rowptr,
                                                 int* __restrict__ perm) {
    __shared__ int deg[512], lptr[512], ssum[256];
    int b = blockIdx.x, t = threadIdx.x;
    int n0 = b << 9;
    int nn = NNODES - n0; if (nn > 512) nn = 512;
    int e0 = binOfs[b], e1 = binOfs[b + 1];
    deg[t] = 0; deg[t + 256] = 0;
    __syncthreads();
    for (int e = e0 + t; e < e1; e += 256)
        atomicAdd(&deg[ebin[e].y - n0], 1);
    __syncthreads();
    int d0 = deg[2 * t], d1 = deg[2 * t + 1];
    int s = d0 + d1;
    ssum[t] = s;
    __syncthreads();
    for (int off = 1; off < 256; off <<= 1) {
        int x = (t >= off) ? ssum[t - off] : 0;
        __syncthreads();
        ssum[t] += x;
        __syncthreads();
    }
    int ex = ssum[t] - s;
    lptr[2 * t] = ex;
    lptr[2 * t + 1] = ex + d0;
    if (2 * t < nn)     rowptr[n0 + 2 * t] = e0 + ex;
    if (2 * t + 1 < nn) rowptr[n0 + 2 * t + 1] = e0 + ex + d0;
    if (b == NB - 1 && t == 0) rowptr[NNODES] = e1;
    deg[2 * t] = 0; deg[2 * t + 1] = 0;   // reuse as cursor
    __syncthreads();
    for (int e = e0 + t; e < e1; e += 256) {
        int2 ed = ebin[e];
        int d = ed.y - n0;
        int pos = e0 + lptr[d] + atomicAdd(&deg[d], 1);
        perm[pos] = ed.x;
    }
}

// ================= gather aggregation (R4 best: 57.0us, at pattern ceiling) ==
__device__ __forceinline__ void accu(f32x2* acc, uint4 u) {
    acc[0] += up2(u.x);
    acc[1] += up2(u.y);
    acc[2] += up2(u.z);
    acc[3] += up2(u.w);
}

template <int S>
__device__ __forceinline__ void gslots(const int* __restrict__ perm, const uint4* __restrict__ F,
                                       int j, int je, int g, int c, f32x2* acc) {
    int pm[S];
#pragma unroll
    for (int k = 0; k < S; k++) pm[k] = perm[j + 4 * k + g];
#pragma unroll
    for (int k = 0; k < S; k++)
        if (j + 4 * k + g >= je) pm[k] = ZROW;       // value-clamp, off the addr-issue path
    uint4 u[S];
#pragma unroll
    for (int k = 0; k < S; k++) u[k] = F[pm[k] * 16 + c];
#pragma unroll
    for (int k = 0; k < S; k++) accu(acc, u[k]);
}

__global__ __launch_bounds__(256) void k_gather(const unsigned short* __restrict__ feat,
                                                const unsigned short* __restrict__ x,
                                                const int* __restrict__ rowptr,
                                                const int* __restrict__ perm,
                                                unsigned short* __restrict__ out) {
    int wave = threadIdx.x >> 6, lane = threadIdx.x & 63;
    int i = blockIdx.x * 4 + wave;        // NNODES = 25000*4 exactly
    int g = lane >> 4, c = lane & 15;
    const uint4* F = (const uint4*)feat;  // one row = 16 uint4

    uint4 xv = ((const uint4*)x)[i * 16 + c];
    int jb = rowptr[i], je = rowptr[i + 1];

    f32x2 acc[4];
#pragma unroll
    for (int k = 0; k < 4; k++) acc[k] = (f32x2){0.f, 0.f};

    int j = jb;
    while (je - j > 24) {
        int s0 = perm[j + g], s1 = perm[j + 4 + g];
        int s2 = perm[j + 8 + g], s3 = perm[j + 12 + g];
        uint4 u0 = F[s0 * 16 + c];
        uint4 u1 = F[s1 * 16 + c];
        uint4 u2 = F[s2 * 16 + c];
        uint4 u3 = F[s3 * 16 + c];
        accu(acc, u0); accu(acc, u1); accu(acc, u2); accu(acc, u3);
        j += 16;
    }
    int deg = je - j;                     // 0..24, wave-uniform
    if (deg > 16)      gslots<6>(perm, F, j, je, g, c, acc);
    else if (deg > 8)  gslots<4>(perm, F, j, je, g, c, acc);
    else if (deg > 0)  gslots<2>(perm, F, j, je, g, c, acc);

#pragma unroll
    for (int k = 0; k < 4; k++) {
        acc[k][0] += __shfl_xor(acc[k][0], 16);
        acc[k][1] += __shfl_xor(acc[k][1], 16);
        acc[k][0] += __shfl_xor(acc[k][0], 32);
        acc[k][1] += __shfl_xor(acc[k][1], 32);
    }

    acc[0] += up2(xv.x);
    acc[1] += up2(xv.y);
    acc[2] += up2(xv.z);
    acc[3] += up2(xv.w);

    if (g == 0) {
        uint4 r;
        r.x = ((unsigned int)f2bf(acc[0][1]) << 16) | f2bf(acc[0][0]);
        r.y = ((unsigned int)f2bf(acc[1][1]) << 16) | f2bf(acc[1][0]);
        r.z = ((unsigned int)f2bf(acc[2][1]) << 16) | f2bf(acc[2][0]);
        r.w = ((unsigned int)f2bf(acc[3][1]) << 16) | f2bf(acc[3][0]);
        ((uint4*)out)[i * 16 + c] = r;
    }
}

// ================= fused GIN MLP v5: out = relu(relu(A@Wa+ba)@Wb+bb) ==========
// v4 (R9) proved the scattered-u16-store write-amp theory: full-line stores
// cut mlp1 62 -> ~22us (total -40). v5 applies the SAME fix to the DOFC fc
// epilogue: stage the 16-row x 40-col result packed into sT (free after the
// a3 reads, ordering guaranteed by data dependency), then copy out linearly
// with uint4 lanes — 2560B (f32) / 1280B (bf16) per tile, r0*160 % 128 == 0,
// all full L2 lines, zero RFO. Weights in swizzled LDS as R8/R9 (proven).
template <bool DOFC>
__global__ __launch_bounds__(256, 2) void k_mlp_lds(const unsigned short* __restrict__ A,
                                                    const unsigned short* __restrict__ WaT,
                                                    const float* __restrict__ ba,
                                                    const unsigned short* __restrict__ WbT,
                                                    const float* __restrict__ bb,
                                                    const unsigned short* __restrict__ WfcT,
                                                    const float* __restrict__ bfc,
                                                    const int* __restrict__ flags,
                                                    unsigned short* __restrict__ outH,
                                                    void* __restrict__ outFC) {
    __shared__ __align__(16) unsigned short sWa[16384];   // 128x128 swizzled
    __shared__ __align__(16) unsigned short sWb[16384];   // 128x128 swizzled
    __shared__ __align__(16) unsigned short sT[4][2048];  // per-wave 16x128 swizzled

    int wave = threadIdx.x >> 6, lane = threadIdx.x & 63;
    int gw = blockIdx.x * 4 + wave;
    int m = lane & 15, quad = lane >> 4;
    unsigned short* T = sT[wave];

    // stage Wa+Wb into swizzled LDS: 16B-chunk permutation -> uint4 copies
    {
        const uint4* Wa4 = (const uint4*)WaT;
        const uint4* Wb4 = (const uint4*)WbT;
        uint4* sA4 = (uint4*)sWa;
        uint4* sB4 = (uint4*)sWb;
        for (int idx = (int)threadIdx.x; idx < 2048; idx += 256) {
            int n = idx >> 4, kc = idx & 15;
            int d = (n << 4) | (kc ^ (n & 15));
            sA4[d] = Wa4[idx];
            sB4[d] = Wb4[idx];
        }
    }

    float bva[8], bvb[8];
#pragma unroll
    for (int nt = 0; nt < 8; nt++) { bva[nt] = ba[nt * 16 + m]; bvb[nt] = bb[nt * 16 + m]; }

    bf16x8 wf[3][4];
    float fv0 = 0.f, fv1 = 0.f, fv2 = 0.f;
    bool valid2 = (m < 8);
    int obf = 0;
    if (DOFC) {
#pragma unroll
        for (int nt = 0; nt < 3; nt++) {
            const unsigned short* Bf = WfcT + (nt * 16 + m) * DF + quad * 8;
#pragma unroll
            for (int ks = 0; ks < 4; ks++) wf[nt][ks] = *(const bf16x8*)(Bf + ks * 32);
        }
        fv0 = bfc[m]; fv1 = bfc[16 + m];
        fv2 = valid2 ? bfc[32 + m] : 0.f;
        obf = flags[1];
    }
    __syncthreads();

    for (int tile = gw; tile < NNODES / 16; tile += MLP_WAVES) {
        int r0 = tile * 16;
        const unsigned short* Ab = A + (r0 + m) * DF + quad * 8;
        bf16x8 a[4];
#pragma unroll
        for (int ks = 0; ks < 4; ks++) a[ks] = *(const bf16x8*)(Ab + ks * 32);

        f32x4 acc[8];
#pragma unroll
        for (int nt = 0; nt < 8; nt++) acc[nt] = (f32x4){0.f, 0.f, 0.f, 0.f};
#pragma unroll
        for (int nt = 0; nt < 8; nt++) {
#pragma unroll
            for (int ks = 0; ks < 4; ks++) {
                bf16x8 w = *(const bf16x8*)&sWa[((nt * 16 + m) << 7) | ((((ks << 2) + quad) ^ m) << 3)];
                acc[nt] = __builtin_amdgcn_mfma_f32_16x16x32_bf16(a[ks], w, acc[nt], 0, 0, 0);
            }
        }

        // stage-1 epilogue -> per-wave tile (relu'd bf16), swizzled scalar writes
#pragma unroll
        for (int nt = 0; nt < 8; nt++)
#pragma unroll
            for (int reg = 0; reg < 4; reg++) {
                float v = acc[nt][reg] + bva[nt];
                if (v < 0.f) v = 0.f;
                int row = quad * 4 + reg, col = nt * 16 + m;
                T[(row << 7) | ((((col >> 3) ^ row) & 15) << 3) | (col & 7)] = f2bf(v);
            }

        // stage-2: A-frags from tile (row m), B-frags from sWb
        bf16x8 a2[4];
#pragma unroll
        for (int ks = 0; ks < 4; ks++)
            a2[ks] = *(const bf16x8*)&T[(m << 7) | ((((ks << 2) + quad) ^ m) << 3)];
#pragma unroll
        for (int nt = 0; nt < 8; nt++) acc[nt] = (f32x4){0.f, 0.f, 0.f, 0.f};
#pragma unroll
        for (int nt = 0; nt < 8; nt++) {
#pragma unroll
            for (int ks = 0; ks < 4; ks++) {
                bf16x8 w = *(const bf16x8*)&sWb[((nt * 16 + m) << 7) | ((((ks << 2) + quad) ^ m) << 3)];
                acc[nt] = __builtin_amdgcn_mfma_f32_16x16x32_bf16(a2[ks], w, acc[nt], 0, 0, 0);
            }
        }

        if (!DOFC) {
            // h -> tile (same swizzle; same-wave DS in-order after a2 reads)
#pragma unroll
            for (int nt = 0; nt < 8; nt++)
#pragma unroll
                for (int reg = 0; reg < 4; reg++) {
                    float v = acc[nt][reg] + bvb[nt];
                    if (v < 0.f) v = 0.f;
                    int row = quad * 4 + reg, col = nt * 16 + m;
                    T[(row << 7) | ((((col >> 3) ^ row) & 15) << 3) | (col & 7)] = f2bf(v);
                }
            // full-line vectorized store: 4 instrs x 8 rows x 128B full lines
            int r2 = lane >> 3, c8 = lane & 7;
            const uint4* T4 = (const uint4*)T;
            uint4* O4 = (uint4*)(outH + (size_t)r0 * DF);
#pragma unroll
            for (int half = 0; half < 2; half++) {
                int row = r2 + half * 8;
#pragma unroll
                for (int lin = 0; lin < 2; lin++) {
                    int ch = c8 + lin * 8;
                    uint4 v = T4[(row << 4) | (ch ^ row)];
                    O4[row * 16 + ch] = v;
                }
            }
        } else {
            // h2 -> tile (same-wave DS ops in-order after the a2 reads)
#pragma unroll
            for (int nt = 0; nt < 8; nt++)
#pragma unroll
                for (int reg = 0; reg < 4; reg++) {
                    float v = acc[nt][reg] + bvb[nt];
                    if (v < 0.f) v = 0.f;
                    int row = quad * 4 + reg, col = nt * 16 + m;
                    T[(row << 7) | ((((col >> 3) ^ row) & 15) << 3) | (col & 7)] = f2bf(v);
                }
            bf16x8 a3[4];
#pragma unroll
            for (int ks = 0; ks < 4; ks++)
                a3[ks] = *(const bf16x8*)&T[(m << 7) | ((((ks << 2) + quad) ^ m) << 3)];
            f32x4 fa[3];
#pragma unroll
            for (int nt = 0; nt < 3; nt++) fa[nt] = (f32x4){0.f, 0.f, 0.f, 0.f};
#pragma unroll
            for (int nt = 0; nt < 3; nt++)
#pragma unroll
                for (int ks = 0; ks < 4; ks++)
                    fa[nt] = __builtin_amdgcn_mfma_f32_16x16x32_bf16(a3[ks], wf[nt][ks], fa[nt], 0, 0, 0);

            // fc + log_softmax -> stage packed 16x40 into T (free after a3
            // reads; ordering by data dependency), then full-line copy out.
            float ov[3][4];   // [colgroup][reg] = v - l
#pragma unroll
            for (int reg = 0; reg < 4; reg++) {
                float v0 = fa[0][reg] + fv0;
                float v1 = fa[1][reg] + fv1;
                float v2 = valid2 ? (fa[2][reg] + fv2) : -3.0e38f;
                float mx = fmaxf(fmaxf(v0, v1), v2);
#pragma unroll
                for (int off = 1; off < 16; off <<= 1) mx = fmaxf(mx, __shfl_xor(mx, off, 16));
                float e = __expf(v0 - mx) + __expf(v1 - mx) + (valid2 ? __expf(v2 - mx) : 0.f);
#pragma unroll
                for (int off = 1; off < 16; off <<= 1) e += __shfl_xor(e, off, 16);
                float l = mx + __logf(e);
                ov[0][reg] = v0 - l;
                ov[1][reg] = v1 - l;
                ov[2][reg] = v2 - l;
            }
            if (obf) {
                unsigned short* Ts = T;              // 16 rows x 40 u16, packed
#pragma unroll
                for (int reg = 0; reg < 4; reg++) {
                    int row = quad * 4 + reg;
                    Ts[row * 40 + m] = f2bf(ov[0][reg]);
                    Ts[row * 40 + 16 + m] = f2bf(ov[1][reg]);
                    if (valid2) Ts[row * 40 + 32 + m] = f2bf(ov[2][reg]);
                }
                // copy 1280B = 80 uint4 (full 128B lines; r0*80 % 128 == 0)
                const uint4* T4 = (const uint4*)Ts;
                uint4* O4 = (uint4*)((unsigned short*)outFC + (size_t)r0 * NC);
#pragma unroll
                for (int it = 0; it < 2; it++) {
                    int idx = it * 64 + lane;
                    if (idx < 80) O4[idx] = T4[idx];
                }
            } else {
                float* Tf = (float*)T;               // 16 rows x 40 f32, packed
#pragma unroll
                for (int reg = 0; reg < 4; reg++) {
                    int row = quad * 4 + reg;
                    Tf[row * 40 + m] = ov[0][reg];
                    Tf[row * 40 + 16 + m] = ov[1][reg];
                    if (valid2) Tf[row * 40 + 32 + m] = ov[2][reg];
                }
                // copy 2560B = 160 uint4 (full 128B lines; r0*160 % 128 == 0)
                const uint4* T4 = (const uint4*)Tf;
                uint4* O4 = (uint4*)((float*)outFC + (size_t)r0 * NC);
#pragma unroll
                for (int it = 0; it < 3; it++) {
                    int idx = it * 64 + lane;
                    if (idx < 160) O4[idx] = T4[idx];
                }
            }
        }
    }
}

extern "C" void kernel_launch(void* const* d_in, const int* in_sizes, int n_in,
                              void* d_out, int out_size, void* d_ws, size_t ws_size,
                              hipStream_t stream) {
    const void* x   = d_in[0];
    const void* ei  = d_in[1];
    const void* w1a = d_in[2];
    const void* b1a = d_in[3];
    const void* w1b = d_in[4];
    const void* b1b = d_in[5];
    const void* w2a = d_in[6];
    const void* b2a = d_in[7];
    const void* w2b = d_in[8];
    const void* b2b = d_in[9];
    const void* wfc = d_in[10];
    const void* bfc = d_in[11];

    char* ws = (char*)d_ws;
    size_t off = 0;
    auto alloc = [&](size_t bytes) {
        void* p = ws + off;
        off += (bytes + 255) & ~(size_t)255;
        return p;
    };
    // B0/B1 have one extra zeroed row (ZROW) for the gather's slot clamp.
    unsigned short* B0    = (unsigned short*)alloc((size_t)(NNODES + 1) * DF * 2);
    unsigned short* B1    = (unsigned short*)alloc((size_t)(NNODES + 1) * DF * 2);
    int2*           ebin  = (int2*)alloc((size_t)NEDGES * 8);
    int*            perm  = (int*)alloc((size_t)(NEDGES + 64) * 4);   // +64 pad: slot over-read
    int*            rowptr= (int*)alloc((size_t)(NNODES + 1) * 4);
    int*            binCnt= (int*)alloc(NB * 4);
    int*            binOfs= (int*)alloc((NB + 1) * 4);
    int*            binCur= (int*)alloc(NB * 4);
    int*            flags = (int*)alloc(256);
    unsigned short* wAll  = (unsigned short*)alloc((4 * 16384 + NCP * 128) * 2);
    float*          bAll  = (float*)alloc((512 + NC) * 4);

    unsigned short* w1aT = wAll;
    unsigned short* w1bT = wAll + 16384;
    unsigned short* w2aT = wAll + 32768;
    unsigned short* w2bT = wAll + 49152;
    unsigned short* wfcT = wAll + 65536;
    float* b1af = bAll;
    float* b1bf = bAll + 128;
    float* b2af = bAll + 256;
    float* b2bf = bAll + 384;
    float* bfcf = bAll + 512;

    // ---- dtype detection (+ binCnt zero), then fused cvt + weight prep + bincount
    k_detect<<<1, 256, 0, stream>>>((const unsigned int*)ei, (const unsigned int*)x, flags, binCnt);
    int prepGrid = CVT_BLOCKS + WPREP_BLOCKS + NEB;
    k_prep<<<prepGrid, 256, 0, stream>>>(x, w1a, w1b, w2a, w2b, wfc,
                                         b1a, b1b, b2a, b2b, bfc, ei,
                                         flags, B0, wAll, bAll,
                                         B0 + (size_t)NNODES * DF,
                                         B1 + (size_t)NNODES * DF,
                                         binCnt);

    // ---- binned CSR build (scan -> scatter -> fill)
    k_binscan<<<1, 256, 0, stream>>>(binCnt, binOfs, binCur);
    k_binscatter<<<NEB, 256, 0, stream>>>(ei, flags, binCur, ebin);
    k_binfill<<<NB, 256, 0, stream>>>(ebin, binOfs, rowptr, perm);

    const int gatherGrid = NNODES / 4;                         // 25000

    // ---- layer 1: gather -> fused MLP (h1 into B0; its ZROW pad stays zero)
    k_gather<<<gatherGrid, 256, 0, stream>>>(B0, B0, rowptr, perm, B1);
    k_mlp_lds<false><<<MLP_BLOCKS, 256, 0, stream>>>(B1, w1aT, b1af, w1bT, b1bf,
                                                     nullptr, nullptr, flags, B0, nullptr);

    // ---- layer 2: gather -> fused MLP + fc + log_softmax (h2 never hits global)
    k_gather<<<gatherGrid, 256, 0, stream>>>(B0, B0, rowptr, perm, B1);
    k_mlp_lds<true><<<MLP_BLOCKS, 256, 0, stream>>>(B1, w2aT, b2af, w2bT, b2bf,
                                                    wfcT, bfcf, flags, nullptr, d_out);
}